// Round 4
// baseline (1254.008 us; speedup 1.0000x reference)
//
#include <hip/hip_runtime.h>
#include <math.h>

// ---------- types ----------
typedef __bf16 bf16x8 __attribute__((ext_vector_type(8)));
typedef float  f32x4  __attribute__((ext_vector_type(4)));

#define QCHUNK 128
#define NCHUNK 16

__device__ __forceinline__ float bf2f(unsigned short u) {
    union { unsigned int i; float f; } v; v.i = ((unsigned int)u) << 16; return v.f;
}
__device__ __forceinline__ unsigned short f2bf(float f) {
    union { float f; unsigned int i; } v; v.f = f;
    unsigned int x = v.i;
    unsigned int r = (x + 0x7FFFu + ((x >> 16) & 1u)) >> 16;
    return (unsigned short)r;
}
__device__ __forceinline__ uint4 pack8(float4 a, float4 b) {
    uint4 r;
    r.x = (unsigned)f2bf(a.x) | ((unsigned)f2bf(a.y) << 16);
    r.y = (unsigned)f2bf(a.z) | ((unsigned)f2bf(a.w) << 16);
    r.z = (unsigned)f2bf(b.x) | ((unsigned)f2bf(b.y) << 16);
    r.w = (unsigned)f2bf(b.z) | ((unsigned)f2bf(b.w) << 16);
    return r;
}

// ---------- GEMM: Out[m,n] = sum_k A[m,k] * Bw[n,k]  (+ optional f32 residual) ----------
template <bool A_F32, bool B_F32, bool OUT_F32, bool RESID>
__global__ __launch_bounds__(256)
void gemm_bt(const void* __restrict__ Ap, const void* __restrict__ Bp,
             void* __restrict__ Outp, const float* __restrict__ Resid,
             int M, int N, int K, int lda, int ldb) {
    __shared__ __align__(16) __bf16 As[128 * 40];
    __shared__ __align__(16) __bf16 Bs[128 * 40];

    const int tid  = threadIdx.x;
    const int m0   = blockIdx.y * 128;
    const int n0   = blockIdx.x * 128;
    const int wave = tid >> 6, lane = tid & 63;
    const int wm   = (wave & 1) * 64, wn = (wave >> 1) * 64;
    const int lr   = lane & 15, q = lane >> 4;

    f32x4 acc[4][4] = {};

    for (int k0 = 0; k0 < K; k0 += 32) {
        #pragma unroll
        for (int c = tid; c < 512; c += 256) {
            int r = c >> 2, k8 = (c & 3) << 3;
            uint4 pa;
            if (A_F32) {
                const float* src = (const float*)Ap + (size_t)(m0 + r) * lda + k0 + k8;
                pa = pack8(*(const float4*)src, *(const float4*)(src + 4));
            } else {
                pa = *(const uint4*)((const unsigned short*)Ap + (size_t)(m0 + r) * lda + k0 + k8);
            }
            *(uint4*)(As + r * 40 + k8) = pa;

            int n = n0 + r;
            uint4 pb = make_uint4(0u, 0u, 0u, 0u);
            if (n < N) {
                if (B_F32) {
                    const float* src = (const float*)Bp + (size_t)n * ldb + k0 + k8;
                    pb = pack8(*(const float4*)src, *(const float4*)(src + 4));
                } else {
                    pb = *(const uint4*)((const unsigned short*)Bp + (size_t)n * ldb + k0 + k8);
                }
            }
            *(uint4*)(Bs + r * 40 + k8) = pb;
        }
        __syncthreads();

        bf16x8 af[4], bfr[4];
        #pragma unroll
        for (int t = 0; t < 4; ++t) {
            af[t]  = *(const bf16x8*)(As + (wm + t * 16 + lr) * 40 + q * 8);
            bfr[t] = *(const bf16x8*)(Bs + (wn + t * 16 + lr) * 40 + q * 8);
        }
        #pragma unroll
        for (int ti = 0; ti < 4; ++ti)
            #pragma unroll
            for (int tj = 0; tj < 4; ++tj)
                acc[ti][tj] = __builtin_amdgcn_mfma_f32_16x16x32_bf16(af[ti], bfr[tj], acc[ti][tj], 0, 0, 0);
        __syncthreads();
    }

    #pragma unroll
    for (int ti = 0; ti < 4; ++ti) {
        #pragma unroll
        for (int r = 0; r < 4; ++r) {
            int m = m0 + wm + ti * 16 + q * 4 + r;
            #pragma unroll
            for (int tj = 0; tj < 4; ++tj) {
                int n = n0 + wn + tj * 16 + lr;
                if (n < N) {
                    float v = acc[ti][tj][r];
                    if (RESID) v += Resid[(size_t)m * N + n];
                    if (OUT_F32) ((float*)Outp)[(size_t)m * N + n] = v;
                    else ((unsigned short*)Outp)[(size_t)m * N + n] = f2bf(v);
                }
            }
        }
    }
}

// ---------- causal depthwise conv(4) + silu, 8 channels/thread ----------
__global__ __launch_bounds__(256)
void conv_silu_kernel(const unsigned short* __restrict__ zx,
                      const float* __restrict__ cw,
                      const float* __restrict__ cb,
                      float* __restrict__ convo) {
    int idx = blockIdx.x * 256 + threadIdx.x;
    if (idx >= 8192 * 224) return;
    int c8 = idx % 224;
    int row = idx / 224;
    int c = c8 << 3;
    int l = row & 2047;                     // L = 2048
    float acc[8];
    #pragma unroll
    for (int i = 0; i < 8; ++i) acc[i] = cb[c + i];
    #pragma unroll
    for (int k = 0; k < 4; ++k) {
        int dl = 3 - k;
        if (l >= dl) {
            const unsigned short* src = zx + (size_t)(row - dl) * 3352 + 1536 + c;
            uint4 v = *(const uint4*)src;
            unsigned short uu[8];
            uu[0] = v.x & 0xFFFF; uu[1] = v.x >> 16;
            uu[2] = v.y & 0xFFFF; uu[3] = v.y >> 16;
            uu[4] = v.z & 0xFFFF; uu[5] = v.w ? (v.z >> 16) : (v.z >> 16); uu[5] = v.z >> 16;
            uu[6] = v.w & 0xFFFF; uu[7] = v.w >> 16;
            #pragma unroll
            for (int i = 0; i < 8; ++i) acc[i] += bf2f(uu[i]) * cw[(c + i) * 4 + k];
        }
    }
    float* dst = convo + (size_t)row * 1792 + c;
    #pragma unroll
    for (int i = 0; i < 8; ++i) { float a = acc[i]; dst[i] = a / (1.f + expf(-a)); }
}

// ---------- dt in full f32 -> interleaved (dt, dA) float2 ----------
__global__ __launch_bounds__(64)
void dt_kernel(const float* __restrict__ x, const float* __restrict__ w_in,
               const float* __restrict__ dt_bias, const float* __restrict__ A_log,
               float2* __restrict__ dtdA) {
    int row = blockIdx.x;
    int lane = threadIdx.x;
    float xv[12];
    #pragma unroll
    for (int i = 0; i < 12; ++i) xv[i] = x[(size_t)row * 768 + i * 64 + lane];
    for (int h = 0; h < 24; ++h) {
        const float* w = w_in + (size_t)(3328 + h) * 768;
        float acc = 0.f;
        #pragma unroll
        for (int i = 0; i < 12; ++i) acc += xv[i] * w[i * 64 + lane];
        #pragma unroll
        for (int m = 1; m < 64; m <<= 1) acc += __shfl_xor(acc, m);
        if (lane == 0) {
            float v = acc + dt_bias[h];
            float dt = (v > 20.f) ? v : log1pf(expf(v));
            float A = -expf(A_log[h]);
            dtdA[(size_t)row * 24 + h] = make_float2(dt, expf(dt * A));
        }
    }
}

// ---------- pass A: per-chunk local scan, software-pipelined ----------
// grid: bh(96) x pg(4) x c(16) = 6144 blocks, 256 threads. Wave = 4 p, 16 lanes/p, 8 n/lane.
__global__ __launch_bounds__(256)
void scan_local_kernel(const float* __restrict__ cv,
                       const float2* __restrict__ dtdA,
                       const float* __restrict__ Dh,
                       float* __restrict__ yb,
                       unsigned short* __restrict__ sst,
                       float* __restrict__ Pbuf) {
    int blk = blockIdx.x;
    int c  = blk & 15;
    int pg = (blk >> 4) & 3;
    int bh = blk >> 6;
    int b = bh / 24, h = bh % 24;
    int wave = threadIdx.x >> 6, lane = threadIdx.x & 63;
    int p = pg * 16 + wave * 4 + (lane >> 4);
    int lr = lane & 15;
    int t0 = c * QCHUNK;

    const float* base = cv + ((size_t)b * 2048 + t0) * 1792;
    const float* xp  = base + h * 64 + p;
    const float* bcp = base + 1536 + lr * 8;          // B at +0, C at +128 floats
    const float2* dd = dtdA + ((size_t)b * 2048 + t0) * 24 + h;
    float Dv = Dh[h];
    float* yp = yb + ((size_t)b * 2048 + t0) * 1536 + h * 64 + p;

    float s[8];
    #pragma unroll
    for (int j = 0; j < 8; ++j) s[j] = 0.f;
    float dAprod = 1.f;

    // preload t = 0
    float  nxv = xp[0];
    float4 nb0 = *(const float4*)(bcp);
    float4 nb1 = *(const float4*)(bcp + 4);
    float4 nc0 = *(const float4*)(bcp + 128);
    float4 nc1 = *(const float4*)(bcp + 132);
    float2 ndd = dd[0];

    for (int t = 0; t < QCHUNK; ++t) {
        float  xv = nxv;
        float4 b0 = nb0, b1 = nb1, c0 = nc0, c1 = nc1;
        float2 dv = ndd;
        int tn = (t + 1) & (QCHUNK - 1);              // wraps to 0 on last iter (harmless reload)
        const float* nb = bcp + (size_t)tn * 1792;
        nxv = xp[(size_t)tn * 1792];
        nb0 = *(const float4*)(nb);
        nb1 = *(const float4*)(nb + 4);
        nc0 = *(const float4*)(nb + 128);
        nc1 = *(const float4*)(nb + 132);
        ndd = dd[tn * 24];

        float dAv = dv.y;
        dAprod *= dAv;
        float dtx = dv.x * xv;
        float bb[8] = {b0.x, b0.y, b0.z, b0.w, b1.x, b1.y, b1.z, b1.w};
        float cc[8] = {c0.x, c0.y, c0.z, c0.w, c1.x, c1.y, c1.z, c1.w};
        float acc = 0.f;
        #pragma unroll
        for (int j = 0; j < 8; ++j) {
            s[j] = s[j] * dAv + dtx * bb[j];
            acc += s[j] * cc[j];
        }
        acc += __shfl_xor(acc, 1);
        acc += __shfl_xor(acc, 2);
        acc += __shfl_xor(acc, 4);
        acc += __shfl_xor(acc, 8);
        if (lr == 0) yp[(size_t)t * 1536] = acc + Dv * xv;
    }

    unsigned short* sp = sst + ((((size_t)bh * NCHUNK + c) * 64 + p) * 128) + lr * 8;
    *(uint4*)sp = pack8(make_float4(s[0], s[1], s[2], s[3]),
                        make_float4(s[4], s[5], s[6], s[7]));
    if (threadIdx.x == 0 && pg == 0) Pbuf[bh * NCHUNK + c] = dAprod;
}

// ---------- pass B: in-place chunk-state combine ----------
__global__ __launch_bounds__(256)
void combine_kernel(unsigned short* __restrict__ sst, const float* __restrict__ Pbuf) {
    int flat = blockIdx.x * 256 + threadIdx.x;   // 96 * 8192 = 786432
    int bh = flat >> 13;
    int pn = flat & 8191;
    unsigned short* sb = sst + (size_t)bh * NCHUNK * 8192 + pn;
    const float* Pb = Pbuf + bh * NCHUNK;
    float s = 0.f;
    #pragma unroll
    for (int c = 0; c < NCHUNK; ++c) {
        unsigned short* q = sb + (size_t)c * 8192;
        float tmp = bf2f(*q);   // s_loc(c)
        *q = f2bf(s);           // becomes s_in(c)
        s = Pb[c] * s + tmp;
    }
}

// ---------- pass C: inter-chunk: y_t += Acum(t) * (C_t . s_in), software-pipelined ----------
// grid: bh(96) x pg(4) x c(15) = 5760 blocks.
__global__ __launch_bounds__(256)
void scan_inter_kernel(const float* __restrict__ cv,
                       const float2* __restrict__ dtdA,
                       const unsigned short* __restrict__ sst,
                       float* __restrict__ yb) {
    int blk = blockIdx.x;
    int rem = blk % 60;
    int bh  = blk / 60;
    int pg  = rem / 15;
    int c   = rem % 15 + 1;
    int b = bh / 24, h = bh % 24;
    int wave = threadIdx.x >> 6, lane = threadIdx.x & 63;
    int p = pg * 16 + wave * 4 + (lane >> 4);
    int lr = lane & 15;
    int t0 = c * QCHUNK;

    const unsigned short* sp = sst + ((((size_t)bh * NCHUNK + c) * 64 + p) * 128) + lr * 8;
    uint4 pk = *(const uint4*)sp;
    float si[8];
    si[0] = bf2f((unsigned short)(pk.x & 0xFFFF)); si[1] = bf2f((unsigned short)(pk.x >> 16));
    si[2] = bf2f((unsigned short)(pk.y & 0xFFFF)); si[3] = bf2f((unsigned short)(pk.y >> 16));
    si[4] = bf2f((unsigned short)(pk.z & 0xFFFF)); si[5] = bf2f((unsigned short)(pk.z >> 16));
    si[6] = bf2f((unsigned short)(pk.w & 0xFFFF)); si[7] = bf2f((unsigned short)(pk.w >> 16));

    const float* cp = cv + ((size_t)b * 2048 + t0) * 1792 + 1664 + lr * 8;
    const float2* dd = dtdA + ((size_t)b * 2048 + t0) * 24 + h;
    float* yp = yb + ((size_t)b * 2048 + t0) * 1536 + h * 64 + p;

    float Acum = 1.f;
    float4 nc0 = *(const float4*)(cp);
    float4 nc1 = *(const float4*)(cp + 4);
    float ndA = dd[0].y;

    for (int t = 0; t < QCHUNK; ++t) {
        float4 c0 = nc0, c1 = nc1;
        float dAv = ndA;
        int tn = (t + 1) & (QCHUNK - 1);
        nc0 = *(const float4*)(cp + (size_t)tn * 1792);
        nc1 = *(const float4*)(cp + (size_t)tn * 1792 + 4);
        ndA = dd[tn * 24].y;

        Acum *= dAv;
        float acc = si[0] * c0.x + si[1] * c0.y + si[2] * c0.z + si[3] * c0.w
                  + si[4] * c1.x + si[5] * c1.y + si[6] * c1.z + si[7] * c1.w;
        acc += __shfl_xor(acc, 1);
        acc += __shfl_xor(acc, 2);
        acc += __shfl_xor(acc, 4);
        acc += __shfl_xor(acc, 8);
        if (lr == 0) yp[(size_t)t * 1536] += Acum * acc;
    }
}

// ---------- gated RMSNorm: writes bf16 into zx cols [1536,3072) (xBC region is dead) ----------
__global__ __launch_bounds__(256)
void norm_kernel(const float* __restrict__ yb,
                 unsigned short* __restrict__ zx,
                 const float* __restrict__ nw) {
    int row = blockIdx.x;
    const float* yr = yb + (size_t)row * 1536;
    unsigned short* zr = zx + (size_t)row * 3352;
    int tid = threadIdx.x;
    float u[6];
    float ss = 0.f;
    #pragma unroll
    for (int i = 0; i < 6; ++i) {
        int c = tid + i * 256;
        float z = bf2f(zr[c]);
        float uu = yr[c] * (z / (1.f + expf(-z)));
        u[i] = uu;
        ss += uu * uu;
    }
    #pragma unroll
    for (int m = 1; m < 64; m <<= 1) ss += __shfl_xor(ss, m);
    __shared__ float red[4];
    if ((tid & 63) == 0) red[tid >> 6] = ss;
    __syncthreads();
    float tot = red[0] + red[1] + red[2] + red[3];
    float inv = rsqrtf(tot * (1.f / 1536.f) + 1e-5f);
    #pragma unroll
    for (int i = 0; i < 6; ++i) {
        int c = tid + i * 256;
        zr[1536 + c] = f2bf(u[i] * inv * nw[c]);
    }
}

// ---------- launch ----------
extern "C" void kernel_launch(void* const* d_in, const int* in_sizes, int n_in,
                              void* d_out, int out_size, void* d_ws, size_t ws_size,
                              hipStream_t stream) {
    const float* x       = (const float*)d_in[0];
    const float* w_in    = (const float*)d_in[1];
    const float* conv_w  = (const float*)d_in[2];
    const float* conv_b  = (const float*)d_in[3];
    const float* dt_bias = (const float*)d_in[4];
    const float* A_log   = (const float*)d_in[5];
    const float* Dp      = (const float*)d_in[6];
    const float* nw      = (const float*)d_in[7];
    const float* w_out   = (const float*)d_in[8];
    float* out = (float*)d_out;

    char* ws = (char*)d_ws;
    const size_t off_zx   = 0;                       // 8192*3352 bf16 = 54,919,168
    const size_t off_conv = off_zx + 54919168;       // 8192*1792 f32  = 58,720,256
    const size_t off_dtdA = off_conv + 58720256;     // 8192*24 float2 = 1,572,864
    const size_t off_y    = off_dtdA + 1572864;      // 8192*1536 f32  = 50,331,648
    const size_t off_sst  = off_y + 50331648;        // 96*16*8192 bf16 = 25,165,824
    const size_t off_P    = off_sst + 25165824;      // 96*16 f32

    unsigned short* zx = (unsigned short*)(ws + off_zx);
    float* cv   = (float*)(ws + off_conv);
    float2* dtdA = (float2*)(ws + off_dtdA);
    float* yb   = (float*)(ws + off_y);
    unsigned short* sst = (unsigned short*)(ws + off_sst);
    float* Pbuf = (float*)(ws + off_P);

    // 1. in_proj (M=8192, N=3352, K=768), f32 in -> bf16 out
    gemm_bt<true, true, false, false><<<dim3(27, 64), 256, 0, stream>>>(x, w_in, zx, nullptr, 8192, 3352, 768, 768, 768);
    // 2. causal depthwise conv + silu
    conv_silu_kernel<<<7168, 256, 0, stream>>>(zx, conv_w, conv_b, cv);
    // 3. dt / dA in full f32
    dt_kernel<<<8192, 64, 0, stream>>>(x, w_in, dt_bias, A_log, dtdA);
    // 4a. chunked scan: local pass
    scan_local_kernel<<<6144, 256, 0, stream>>>(cv, dtdA, Dp, yb, sst, Pbuf);
    // 4b. chunk-state combine
    combine_kernel<<<3072, 256, 0, stream>>>(sst, Pbuf);
    // 4c. inter-chunk correction
    scan_inter_kernel<<<5760, 256, 0, stream>>>(cv, dtdA, sst, yb);
    // 5. gated RMSNorm -> bf16 into zx cols [1536,3072)
    norm_kernel<<<8192, 256, 0, stream>>>(yb, zx, nw);
    // 6. out_proj + residual (A = normed y, bf16, lda=3352)
    gemm_bt<false, true, true, true><<<dim3(6, 64), 256, 0, stream>>>(zx + 1536, w_out, out, x, 8192, 768, 1536, 3352, 1536);
}

// Round 5
// 700.626 us; speedup vs baseline: 1.7898x; 1.7898x over previous
//
#include <hip/hip_runtime.h>
#include <math.h>

// ---------- types ----------
typedef __bf16 bf16x8 __attribute__((ext_vector_type(8)));
typedef float  f32x4  __attribute__((ext_vector_type(4)));

#define QCHUNK 128
#define NCHUNK 16
#define SLD 136              // LDS row stride (bf16 elems) for 128-wide arrays; 272 B = 17*16

__device__ __forceinline__ float bf2f(unsigned short u) {
    union { unsigned int i; float f; } v; v.i = ((unsigned int)u) << 16; return v.f;
}
__device__ __forceinline__ unsigned short f2bf(float f) {
    union { float f; unsigned int i; } v; v.f = f;
    unsigned int x = v.i;
    unsigned int r = (x + 0x7FFFu + ((x >> 16) & 1u)) >> 16;
    return (unsigned short)r;
}
__device__ __forceinline__ uint4 pack8(float4 a, float4 b) {
    uint4 r;
    r.x = (unsigned)f2bf(a.x) | ((unsigned)f2bf(a.y) << 16);
    r.y = (unsigned)f2bf(a.z) | ((unsigned)f2bf(a.w) << 16);
    r.z = (unsigned)f2bf(b.x) | ((unsigned)f2bf(b.y) << 16);
    r.w = (unsigned)f2bf(b.z) | ((unsigned)f2bf(b.w) << 16);
    return r;
}

// ---------- GEMM: Out[m,n] = sum_k A[m,k] * Bw[n,k]  (+ optional f32 residual) ----------
template <bool A_F32, bool B_F32, bool OUT_F32, bool RESID>
__global__ __launch_bounds__(256)
void gemm_bt(const void* __restrict__ Ap, const void* __restrict__ Bp,
             void* __restrict__ Outp, const float* __restrict__ Resid,
             int M, int N, int K, int lda, int ldb) {
    __shared__ __align__(16) __bf16 As[128 * 40];
    __shared__ __align__(16) __bf16 Bs[128 * 40];

    const int tid  = threadIdx.x;
    const int m0   = blockIdx.y * 128;
    const int n0   = blockIdx.x * 128;
    const int wave = tid >> 6, lane = tid & 63;
    const int wm   = (wave & 1) * 64, wn = (wave >> 1) * 64;
    const int lr   = lane & 15, q = lane >> 4;

    f32x4 acc[4][4] = {};

    for (int k0 = 0; k0 < K; k0 += 32) {
        #pragma unroll
        for (int c = tid; c < 512; c += 256) {
            int r = c >> 2, k8 = (c & 3) << 3;
            uint4 pa;
            if (A_F32) {
                const float* src = (const float*)Ap + (size_t)(m0 + r) * lda + k0 + k8;
                pa = pack8(*(const float4*)src, *(const float4*)(src + 4));
            } else {
                pa = *(const uint4*)((const unsigned short*)Ap + (size_t)(m0 + r) * lda + k0 + k8);
            }
            *(uint4*)(As + r * 40 + k8) = pa;

            int n = n0 + r;
            uint4 pb = make_uint4(0u, 0u, 0u, 0u);
            if (n < N) {
                if (B_F32) {
                    const float* src = (const float*)Bp + (size_t)n * ldb + k0 + k8;
                    pb = pack8(*(const float4*)src, *(const float4*)(src + 4));
                } else {
                    pb = *(const uint4*)((const unsigned short*)Bp + (size_t)n * ldb + k0 + k8);
                }
            }
            *(uint4*)(Bs + r * 40 + k8) = pb;
        }
        __syncthreads();

        bf16x8 af[4], bfr[4];
        #pragma unroll
        for (int t = 0; t < 4; ++t) {
            af[t]  = *(const bf16x8*)(As + (wm + t * 16 + lr) * 40 + q * 8);
            bfr[t] = *(const bf16x8*)(Bs + (wn + t * 16 + lr) * 40 + q * 8);
        }
        #pragma unroll
        for (int ti = 0; ti < 4; ++ti)
            #pragma unroll
            for (int tj = 0; tj < 4; ++tj)
                acc[ti][tj] = __builtin_amdgcn_mfma_f32_16x16x32_bf16(af[ti], bfr[tj], acc[ti][tj], 0, 0, 0);
        __syncthreads();
    }

    #pragma unroll
    for (int ti = 0; ti < 4; ++ti) {
        #pragma unroll
        for (int r = 0; r < 4; ++r) {
            int m = m0 + wm + ti * 16 + q * 4 + r;
            #pragma unroll
            for (int tj = 0; tj < 4; ++tj) {
                int n = n0 + wn + tj * 16 + lr;
                if (n < N) {
                    float v = acc[ti][tj][r];
                    if (RESID) v += Resid[(size_t)m * N + n];
                    if (OUT_F32) ((float*)Outp)[(size_t)m * N + n] = v;
                    else ((unsigned short*)Outp)[(size_t)m * N + n] = f2bf(v);
                }
            }
        }
    }
}

// ---------- causal depthwise conv(4) + silu, 8 channels/thread ----------
__global__ __launch_bounds__(256)
void conv_silu_kernel(const unsigned short* __restrict__ zx,
                      const float* __restrict__ cw,
                      const float* __restrict__ cb,
                      float* __restrict__ convo) {
    int idx = blockIdx.x * 256 + threadIdx.x;
    if (idx >= 8192 * 224) return;
    int c8 = idx % 224;
    int row = idx / 224;
    int c = c8 << 3;
    int l = row & 2047;                     // L = 2048
    float acc[8];
    #pragma unroll
    for (int i = 0; i < 8; ++i) acc[i] = cb[c + i];
    #pragma unroll
    for (int k = 0; k < 4; ++k) {
        int dl = 3 - k;
        if (l >= dl) {
            const unsigned short* src = zx + (size_t)(row - dl) * 3352 + 1536 + c;
            uint4 v = *(const uint4*)src;
            unsigned short uu[8];
            uu[0] = v.x & 0xFFFF; uu[1] = v.x >> 16;
            uu[2] = v.y & 0xFFFF; uu[3] = v.y >> 16;
            uu[4] = v.z & 0xFFFF; uu[5] = v.z >> 16;
            uu[6] = v.w & 0xFFFF; uu[7] = v.w >> 16;
            #pragma unroll
            for (int i = 0; i < 8; ++i) acc[i] += bf2f(uu[i]) * cw[(c + i) * 4 + k];
        }
    }
    float* dst = convo + (size_t)row * 1792 + c;
    #pragma unroll
    for (int i = 0; i < 8; ++i) { float a = acc[i]; dst[i] = a / (1.f + expf(-a)); }
}

// ---------- dt in full f32 -> interleaved (dt, dt*A) float2 ----------
__global__ __launch_bounds__(64)
void dt_kernel(const float* __restrict__ x, const float* __restrict__ w_in,
               const float* __restrict__ dt_bias, const float* __restrict__ A_log,
               float2* __restrict__ dtdA) {
    int row = blockIdx.x;
    int lane = threadIdx.x;
    float xv[12];
    #pragma unroll
    for (int i = 0; i < 12; ++i) xv[i] = x[(size_t)row * 768 + i * 64 + lane];
    for (int h = 0; h < 24; ++h) {
        const float* w = w_in + (size_t)(3328 + h) * 768;
        float acc = 0.f;
        #pragma unroll
        for (int i = 0; i < 12; ++i) acc += xv[i] * w[i * 64 + lane];
        #pragma unroll
        for (int m = 1; m < 64; m <<= 1) acc += __shfl_xor(acc, m);
        if (lane == 0) {
            float v = acc + dt_bias[h];
            float dt = (v > 20.f) ? v : log1pf(expf(v));
            float A = -expf(A_log[h]);
            dtdA[(size_t)row * 24 + h] = make_float2(dt, dt * A);   // (dt, log dA)
        }
    }
}

// ---------- tiled transpose: cv (f32 [row][ch]) -> xT/bT (bf16 [ch][t]) ----------
// grid: 4 b x 26 ch-tiles x 32 t-tiles; tile 64x64.
__global__ __launch_bounds__(256)
void transpose_kernel(const float* __restrict__ cv,
                      unsigned short* __restrict__ xT,
                      unsigned short* __restrict__ bT) {
    __shared__ __bf16 tile[64][74];
    int blk = blockIdx.x;
    int tt  = blk & 31;
    int cht = (blk >> 5) % 26;
    int b   = blk / (32 * 26);
    int ch0 = cht * 64, t0 = tt * 64;
    int tx = threadIdx.x & 63, ty4 = threadIdx.x >> 6;

    const float* src = cv + ((size_t)(b * 2048 + t0)) * 1792 + ch0;
    #pragma unroll
    for (int k = 0; k < 16; ++k) {
        int i = ty4 * 16 + k;               // t-local row
        tile[i][tx] = (__bf16)f2bf(0.f), tile[i][tx] = *(__bf16*)&(unsigned short&)*(unsigned short*)0, tile[i][tx];
    }
    // (re-written cleanly below; the above line is dead-stripped)
    #pragma unroll
    for (int k = 0; k < 16; ++k) {
        int i = ty4 * 16 + k;
        float v = src[(size_t)i * 1792 + tx];
        unsigned short u = f2bf(v);
        tile[i][tx] = *(__bf16*)&u;
    }
    __syncthreads();
    #pragma unroll
    for (int k = 0; k < 16; ++k) {
        int chl = ty4 * 16 + k;             // channel-local row of output
        __bf16 bv = tile[tx][chl];
        unsigned short u = *(unsigned short*)&bv;
        int ch = ch0 + chl;
        if (ch < 1536)
            xT[((size_t)(b * 1536 + ch)) * 2048 + t0 + tx] = u;
        else
            bT[((size_t)(b * 128 + ch - 1536)) * 2048 + t0 + tx] = u;
    }
}

// ---------- SSD local kernel: per (b,h,chunk): G -> M -> Y, s_out ----------
// dynamic LDS 70656 B. grid 1536 (bh*16 + c), 256 threads.
__global__ __launch_bounds__(256)
void ssd_local_kernel(const float* __restrict__ cv,
                      const float2* __restrict__ dtdA,
                      const unsigned short* __restrict__ xT,
                      const unsigned short* __restrict__ bT,
                      const float* __restrict__ Dh,
                      float* __restrict__ yb,
                      unsigned short* __restrict__ sst,
                      float* __restrict__ Pbuf) {
    extern __shared__ __align__(16) char smem[];
    __bf16* Bs  = (__bf16*)smem;                 // 128 x SLD  (34816 B); later Xt(0:17408)+Xtw(17408:34816)
    __bf16* Cs  = (__bf16*)(smem + 34816);       // 128 x SLD; later Ms
    float*  Lc  = (float*)(smem + 69632);        // 128
    float*  dtl = (float*)(smem + 70144);        // 128

    const int tid = threadIdx.x;
    const int c   = blockIdx.x & 15;
    const int bh  = blockIdx.x >> 4;
    const int b   = bh / 24, h = bh % 24;
    const int t0g = b * 2048 + c * QCHUNK;
    const int wave = tid >> 6, lane = tid & 63;
    const int lr = lane & 15, q = lane >> 4;

    // P0: stage Bs[tau][n], Cs[t][n] (f32 -> bf16)
    const float* cvb = cv + (size_t)t0g * 1792;
    for (int cc = tid; cc < 2048; cc += 256) {
        int r = cc >> 4, c8 = (cc & 15) << 3;
        const float* sB = cvb + (size_t)r * 1792 + 1536 + c8;
        *(uint4*)(Bs + r * SLD + c8) = pack8(*(const float4*)sB, *(const float4*)(sB + 4));
        const float* sC = cvb + (size_t)r * 1792 + 1664 + c8;
        *(uint4*)(Cs + r * SLD + c8) = pack8(*(const float4*)sC, *(const float4*)(sC + 4));
    }
    if (tid < 128) {
        float2 dd = dtdA[((size_t)t0g + tid) * 24 + h];
        dtl[tid] = dd.x;
        Lc[tid]  = dd.y;     // log dA
    }
    __syncthreads();
    // inclusive prefix sum of Lc
    for (int off = 1; off < 128; off <<= 1) {
        float v = 0.f;
        if (tid < 128 && tid >= off) v = Lc[tid - off];
        __syncthreads();
        if (tid < 128) Lc[tid] += v;
        __syncthreads();
    }

    // P1: G = Cs . Bs^T  (contract n, K=128). 4 waves 2x2, wave tile 64x64.
    const int wm = (wave & 1) * 64, wn = (wave >> 1) * 64;
    f32x4 g[4][4] = {};
    #pragma unroll
    for (int k0 = 0; k0 < 128; k0 += 32) {
        bf16x8 af[4], bfr[4];
        #pragma unroll
        for (int t = 0; t < 4; ++t) {
            af[t]  = *(const bf16x8*)(Cs + (wm + t * 16 + lr) * SLD + k0 + q * 8);
            bfr[t] = *(const bf16x8*)(Bs + (wn + t * 16 + lr) * SLD + k0 + q * 8);
        }
        #pragma unroll
        for (int ti = 0; ti < 4; ++ti)
            #pragma unroll
            for (int tj = 0; tj < 4; ++tj)
                g[ti][tj] = __builtin_amdgcn_mfma_f32_16x16x32_bf16(af[ti], bfr[tj], g[ti][tj], 0, 0, 0);
    }
    __syncthreads();   // Bs, Cs dead

    // P5: masked scale -> Ms[t][tau] (over Cs region)
    __bf16* Ms = Cs;
    {
        float lt_[4], dt_[4];
        #pragma unroll
        for (int tj = 0; tj < 4; ++tj) {
            int tau = wn + tj * 16 + lr;
            lt_[tj] = Lc[tau];
            dt_[tj] = dtl[tau];
        }
        #pragma unroll
        for (int ti = 0; ti < 4; ++ti) {
            #pragma unroll
            for (int r = 0; r < 4; ++r) {
                int t = wm + ti * 16 + q * 4 + r;
                float Lt = Lc[t];
                #pragma unroll
                for (int tj = 0; tj < 4; ++tj) {
                    int tau = wn + tj * 16 + lr;
                    float mv = (tau <= t) ? g[ti][tj][r] * expf(Lt - lt_[tj]) * dt_[tj] : 0.f;
                    unsigned short u = f2bf(mv);
                    Ms[t * SLD + tau] = *(__bf16*)&u;
                }
            }
        }
    }

    // P3: stage Xt[p][t] (raw) and Xtw[p][t] (weighted) from xT
    __bf16* Xt  = Bs;
    __bf16* Xtw = (__bf16*)(smem + 17408);
    {
        float LQ = Lc[127];
        const unsigned short* xTb = xT + ((size_t)(b * 1536 + h * 64)) * 2048 + c * QCHUNK;
        for (int cc = tid; cc < 1024; cc += 256) {
            int p = cc >> 4, c8 = (cc & 15) << 3;
            uint4 v = *(const uint4*)(xTb + (size_t)p * 2048 + c8);
            *(uint4*)(Xt + p * SLD + c8) = v;
            unsigned short uu[8] = {(unsigned short)(v.x & 0xFFFF), (unsigned short)(v.x >> 16),
                                    (unsigned short)(v.y & 0xFFFF), (unsigned short)(v.y >> 16),
                                    (unsigned short)(v.z & 0xFFFF), (unsigned short)(v.z >> 16),
                                    (unsigned short)(v.w & 0xFFFF), (unsigned short)(v.w >> 16)};
            float w0[8];
            #pragma unroll
            for (int j = 0; j < 8; ++j) {
                int tau = c8 + j;
                w0[j] = bf2f(uu[j]) * expf(LQ - Lc[tau]) * dtl[tau];
            }
            *(uint4*)(Xtw + p * SLD + c8) = pack8(make_float4(w0[0], w0[1], w0[2], w0[3]),
                                                  make_float4(w0[4], w0[5], w0[6], w0[7]));
        }
    }
    __syncthreads();

    // P4: s_out[n][p] = sum_tau bT[n][tau] * Xtw[p][tau].  Waves stacked: wave w -> n rows [w*32, w*32+32)
    {
        f32x4 so[2][4] = {};
        const unsigned short* bTb = bT + ((size_t)(b * 128)) * 2048 + c * QCHUNK;
        #pragma unroll
        for (int k0 = 0; k0 < 128; k0 += 32) {
            bf16x8 af[2], bfr[4];
            #pragma unroll
            for (int ti = 0; ti < 2; ++ti) {
                int n = wave * 32 + ti * 16 + lr;
                af[ti] = *(const bf16x8*)(bTb + (size_t)n * 2048 + k0 + q * 8);
            }
            #pragma unroll
            for (int tj = 0; tj < 4; ++tj)
                bfr[tj] = *(const bf16x8*)(Xtw + (tj * 16 + lr) * SLD + k0 + q * 8);
            #pragma unroll
            for (int ti = 0; ti < 2; ++ti)
                #pragma unroll
                for (int tj = 0; tj < 4; ++tj)
                    so[ti][tj] = __builtin_amdgcn_mfma_f32_16x16x32_bf16(af[ti], bfr[tj], so[ti][tj], 0, 0, 0);
        }
        unsigned short* sb = sst + ((size_t)(bh * NCHUNK + c)) * 8192;
        #pragma unroll
        for (int ti = 0; ti < 2; ++ti) {
            #pragma unroll
            for (int r = 0; r < 4; ++r) {
                int n = wave * 32 + ti * 16 + q * 4 + r;
                #pragma unroll
                for (int tj = 0; tj < 4; ++tj) {
                    int p = tj * 16 + lr;
                    sb[n * 64 + p] = f2bf(so[ti][tj][r]);
                }
            }
        }
        if (tid == 0) Pbuf[bh * NCHUNK + c] = expf(Lc[127]);
    }

    // P6: Y[t][p] = sum_tau Ms[t][tau] * Xt[p][tau]
    {
        f32x4 ya[2][4] = {};
        #pragma unroll
        for (int k0 = 0; k0 < 128; k0 += 32) {
            bf16x8 af[2], bfr[4];
            #pragma unroll
            for (int ti = 0; ti < 2; ++ti)
                af[ti] = *(const bf16x8*)(Ms + (wave * 32 + ti * 16 + lr) * SLD + k0 + q * 8);
            #pragma unroll
            for (int tj = 0; tj < 4; ++tj)
                bfr[tj] = *(const bf16x8*)(Xt + (tj * 16 + lr) * SLD + k0 + q * 8);
            #pragma unroll
            for (int ti = 0; ti < 2; ++ti)
                #pragma unroll
                for (int tj = 0; tj < 4; ++tj)
                    ya[ti][tj] = __builtin_amdgcn_mfma_f32_16x16x32_bf16(af[ti], bfr[tj], ya[ti][tj], 0, 0, 0);
        }
        float Dv = Dh[h];
        float* ybb = yb + (size_t)t0g * 1536 + h * 64;
        #pragma unroll
        for (int ti = 0; ti < 2; ++ti) {
            #pragma unroll
            for (int r = 0; r < 4; ++r) {
                int t = wave * 32 + ti * 16 + q * 4 + r;
                #pragma unroll
                for (int tj = 0; tj < 4; ++tj) {
                    int p = tj * 16 + lr;
                    __bf16 xb = Xt[p * SLD + t];
                    float xv = bf2f(*(unsigned short*)&xb);
                    ybb[(size_t)t * 1536 + p] = ya[ti][tj][r] + Dv * xv;
                }
            }
        }
    }
}

// ---------- combine: sequential over chunks; reads sst[c][n][p], writes s_in to sstT[c][p][n] ----------
__global__ __launch_bounds__(256)
void combine_kernel(const unsigned short* __restrict__ sst,
                    unsigned short* __restrict__ sstT,
                    const float* __restrict__ Pbuf) {
    int flat = blockIdx.x * 256 + threadIdx.x;   // 96 * 8192
    int bh = flat >> 13;
    int pn = flat & 8191;                        // = n*64 + p
    int n = pn >> 6, p = pn & 63;
    const unsigned short* sb = sst + (size_t)bh * NCHUNK * 8192;
    unsigned short* tb = sstT + (size_t)bh * NCHUNK * 8192 + p * 128 + n;
    const float* Pb = Pbuf + bh * NCHUNK;
    float s = 0.f;
    #pragma unroll
    for (int c = 0; c < NCHUNK; ++c) {
        float tmp = bf2f(sb[(size_t)c * 8192 + pn]);
        tb[(size_t)c * 8192] = f2bf(s);
        s = Pb[c] * s + tmp;
    }
}

// ---------- SSD inter kernel: y[t][p] += exp(Lc[t]) * sum_n C[t][n]*s_in[p][n] ----------
// grid 1440 (bh*15 + (c-1)), 256 threads. static LDS ~53 KB.
__global__ __launch_bounds__(256)
void ssd_inter_kernel(const float* __restrict__ cv,
                      const float2* __restrict__ dtdA,
                      const unsigned short* __restrict__ sstT,
                      float* __restrict__ yb) {
    __shared__ __align__(16) __bf16 Cs[128 * SLD];   // 34816 B
    __shared__ __align__(16) __bf16 St[64 * SLD];    // 17408 B
    __shared__ float Lc[128];

    const int tid = threadIdx.x;
    const int blk = blockIdx.x;
    const int bh = blk / 15;
    const int c  = blk % 15 + 1;
    const int b = bh / 24, h = bh % 24;
    const int t0g = b * 2048 + c * QCHUNK;
    const int wave = tid >> 6, lane = tid & 63;
    const int lr = lane & 15, q = lane >> 4;

    const float* cvb = cv + (size_t)t0g * 1792;
    for (int cc = tid; cc < 2048; cc += 256) {
        int r = cc >> 4, c8 = (cc & 15) << 3;
        const float* sC = cvb + (size_t)r * 1792 + 1664 + c8;
        *(uint4*)(Cs + r * SLD + c8) = pack8(*(const float4*)sC, *(const float4*)(sC + 4));
    }
    const unsigned short* stb = sstT + ((size_t)(bh * NCHUNK + c)) * 8192;
    for (int cc = tid; cc < 1024; cc += 256) {
        int p = cc >> 4, c8 = (cc & 15) << 3;
        *(uint4*)(St + p * SLD + c8) = *(const uint4*)(stb + p * 128 + c8);
    }
    if (tid < 128) Lc[tid] = dtdA[((size_t)t0g + tid) * 24 + h].y;
    __syncthreads();
    for (int off = 1; off < 128; off <<= 1) {
        float v = 0.f;
        if (tid < 128 && tid >= off) v = Lc[tid - off];
        __syncthreads();
        if (tid < 128) Lc[tid] += v;
        __syncthreads();
    }

    f32x4 ya[2][4] = {};
    #pragma unroll
    for (int k0 = 0; k0 < 128; k0 += 32) {
        bf16x8 af[2], bfr[4];
        #pragma unroll
        for (int ti = 0; ti < 2; ++ti)
            af[ti] = *(const bf16x8*)(Cs + (wave * 32 + ti * 16 + lr) * SLD + k0 + q * 8);
        #pragma unroll
        for (int tj = 0; tj < 4; ++tj)
            bfr[tj] = *(const bf16x8*)(St + (tj * 16 + lr) * SLD + k0 + q * 8);
        #pragma unroll
        for (int ti = 0; ti < 2; ++ti)
            #pragma unroll
            for (int tj = 0; tj < 4; ++tj)
                ya[ti][tj] = __builtin_amdgcn_mfma_f32_16x16x32_bf16(af[ti], bfr[tj], ya[ti][tj], 0, 0, 0);
    }
    float* ybb = yb + (size_t)t0g * 1536 + h * 64;
    #pragma unroll
    for (int ti = 0; ti < 2; ++ti) {
        #pragma unroll
        for (int r = 0; r < 4; ++r) {
            int t = wave * 32 + ti * 16 + q * 4 + r;
            float sc = expf(Lc[t]);
            #pragma unroll
            for (int tj = 0; tj < 4; ++tj) {
                int p = tj * 16 + lr;
                float* yp = ybb + (size_t)t * 1536 + p;
                *yp = *yp + sc * ya[ti][tj][r];
            }
        }
    }
}

// ---------- gated RMSNorm: writes bf16 into zx cols [1536,3072) (xBC region is dead) ----------
__global__ __launch_bounds__(256)
void norm_kernel(const float* __restrict__ yb,
                 unsigned short* __restrict__ zx,
                 const float* __restrict__ nw) {
    int row = blockIdx.x;
    const float* yr = yb + (size_t)row * 1536;
    unsigned short* zr = zx + (size_t)row * 3352;
    int tid = threadIdx.x;
    float u[6];
    float ss = 0.f;
    #pragma unroll
    for (int i = 0; i < 6; ++i) {
        int c = tid + i * 256;
        float z = bf2f(zr[c]);
        float uu = yr[c] * (z / (1.f + expf(-z)));
        u[i] = uu;
        ss += uu * uu;
    }
    #pragma unroll
    for (int m = 1; m < 64; m <<= 1) ss += __shfl_xor(ss, m);
    __shared__ float red[4];
    if ((tid & 63) == 0) red[tid >> 6] = ss;
    __syncthreads();
    float tot = red[0] + red[1] + red[2] + red[3];
    float inv = rsqrtf(tot * (1.f / 1536.f) + 1e-5f);
    #pragma unroll
    for (int i = 0; i < 6; ++i) {
        int c = tid + i * 256;
        zr[1536 + c] = f2bf(u[i] * inv * nw[c]);
    }
}

// ---------- launch ----------
extern "C" void kernel_launch(void* const* d_in, const int* in_sizes, int n_in,
                              void* d_out, int out_size, void* d_ws, size_t ws_size,
                              hipStream_t stream) {
    const float* x       = (const float*)d_in[0];
    const float* w_in    = (const float*)d_in[1];
    const float* conv_w  = (const float*)d_in[2];
    const float* conv_b  = (const float*)d_in[3];
    const float* dt_bias = (const float*)d_in[4];
    const float* A_log   = (const float*)d_in[5];
    const float* Dp      = (const float*)d_in[6];
    const float* nw      = (const float*)d_in[7];
    const float* w_out   = (const float*)d_in[8];
    float* out = (float*)d_out;

    char* ws = (char*)d_ws;
    const size_t off_zx   = 0;                        // 8192*3352 bf16 = 54,919,168
    const size_t off_conv = off_zx + 54919168;        // 8192*1792 f32  = 58,720,256
    const size_t off_dtdA = off_conv + 58720256;      // 8192*24 float2 = 1,572,864
    const size_t off_y    = off_dtdA + 1572864;       // 8192*1536 f32  = 50,331,648
    const size_t off_sst  = off_y + 50331648;         // 96*16*8192 bf16 = 25,165,824
    const size_t off_xT   = off_sst + 25165824;       // 96*64*2048 bf16 = 25,165,824 (reused as sstT)
    const size_t off_bT   = off_xT + 25165824;        // 4*128*2048 bf16 = 2,097,152
    const size_t off_P    = off_bT + 2097152;         // 96*16 f32

    unsigned short* zx  = (unsigned short*)(ws + off_zx);
    float* cv    = (float*)(ws + off_conv);
    float2* dtdA = (float2*)(ws + off_dtdA);
    float* yb    = (float*)(ws + off_y);
    unsigned short* sst  = (unsigned short*)(ws + off_sst);
    unsigned short* xT   = (unsigned short*)(ws + off_xT);
    unsigned short* sstT = xT;                        // xT dead after ssd_local
    unsigned short* bT   = (unsigned short*)(ws + off_bT);
    float* Pbuf = (float*)(ws + off_P);

    static bool attr_set = false;
    if (!attr_set) {
        hipFuncSetAttribute((const void*)ssd_local_kernel,
                            hipFuncAttributeMaxDynamicSharedMemorySize, 70656);
        attr_set = true;
    }

    // 1. in_proj (M=8192, N=3352, K=768)
    gemm_bt<true, true, false, false><<<dim3(27, 64), 256, 0, stream>>>(x, w_in, zx, nullptr, 8192, 3352, 768, 768, 768);
    // 2. conv + silu
    conv_silu_kernel<<<7168, 256, 0, stream>>>(zx, conv_w, conv_b, cv);
    // 3. dt / log-dA
    dt_kernel<<<8192, 64, 0, stream>>>(x, w_in, dt_bias, A_log, dtdA);
    // 4. transpose x/B regions of cv -> xT, bT (bf16)
    transpose_kernel<<<3328, 256, 0, stream>>>(cv, xT, bT);
    // 5. SSD local (y_local + s_out + P)
    ssd_local_kernel<<<1536, 256, 70656, stream>>>(cv, dtdA, xT, bT, Dp, yb, sst, Pbuf);
    // 6. combine (s_loc -> s_in, transposed into sstT)
    combine_kernel<<<3072, 256, 0, stream>>>(sst, sstT, Pbuf);
    // 7. SSD inter-chunk correction
    ssd_inter_kernel<<<1440, 256, 0, stream>>>(cv, dtdA, sstT, yb);
    // 8. gated RMSNorm -> bf16 into zx cols [1536,3072)
    norm_kernel<<<8192, 256, 0, stream>>>(yb, zx, nw);
    // 9. out_proj + residual
    gemm_bt<false, true, true, true><<<dim3(6, 64), 256, 0, stream>>>(zx + 1536, w_out, out, x, 8192, 768, 1536, 3352, 1536);
}

// Round 6
// 565.222 us; speedup vs baseline: 2.2186x; 1.2396x over previous
//
#include <hip/hip_runtime.h>
#include <math.h>

// ---------- types ----------
typedef __bf16 bf16x8 __attribute__((ext_vector_type(8)));
typedef float  f32x4  __attribute__((ext_vector_type(4)));

#define QCHUNK 128
#define NCHUNK 16
#define SLD 136              // LDS row stride (bf16 elems) for 128-wide arrays

__device__ __forceinline__ float bf2f(unsigned short u) {
    union { unsigned int i; float f; } v; v.i = ((unsigned int)u) << 16; return v.f;
}
__device__ __forceinline__ unsigned short f2bf(float f) {
    union { float f; unsigned int i; } v; v.f = f;
    unsigned int x = v.i;
    unsigned int r = (x + 0x7FFFu + ((x >> 16) & 1u)) >> 16;
    return (unsigned short)r;
}
__device__ __forceinline__ uint4 pack8(float4 a, float4 b) {
    uint4 r;
    r.x = (unsigned)f2bf(a.x) | ((unsigned)f2bf(a.y) << 16);
    r.y = (unsigned)f2bf(a.z) | ((unsigned)f2bf(a.w) << 16);
    r.z = (unsigned)f2bf(b.x) | ((unsigned)f2bf(b.y) << 16);
    r.w = (unsigned)f2bf(b.z) | ((unsigned)f2bf(b.w) << 16);
    return r;
}
__device__ __forceinline__ void load_lds16(const void* g, void* l) {
    __builtin_amdgcn_global_load_lds((const __attribute__((address_space(1))) void*)g,
                                     (__attribute__((address_space(3))) void*)l,
                                     16, 0, 0);
}

// ---------- convert: x -> x_bf, w_in -> w_in_bf (padded 3456 rows, zero-filled) ----------
__global__ __launch_bounds__(256)
void convert_kernel(const float* __restrict__ x, const float* __restrict__ w_in,
                    unsigned short* __restrict__ x_bf, unsigned short* __restrict__ w_in_bf) {
    int idx = blockIdx.x * 256 + threadIdx.x;      // 8 elems each
    const int NX  = 8192 * 768 / 8;                // 786432
    const int NW1 = 3456 * 768 / 8;                // 331776 (padded)
    const int NW1r = 3352 * 768 / 8;               // 321792 (real)
    if (idx < NX) {
        const float* s = x + (size_t)idx * 8;
        *(uint4*)(x_bf + (size_t)idx * 8) = pack8(*(const float4*)s, *(const float4*)(s + 4));
    } else if (idx < NX + NW1) {
        int j = idx - NX;
        uint4 v = make_uint4(0u, 0u, 0u, 0u);
        if (j < NW1r) {
            const float* s = w_in + (size_t)j * 8;
            v = pack8(*(const float4*)s, *(const float4*)(s + 4));
        }
        *(uint4*)(w_in_bf + (size_t)j * 8) = v;
    }
}

// ---------- convert w_out -> bf16 (runs late, into dead cv region) ----------
__global__ __launch_bounds__(256)
void convert_wout_kernel(const float* __restrict__ w_out, unsigned short* __restrict__ w_out_bf) {
    int idx = blockIdx.x * 256 + threadIdx.x;      // 147456 total
    const float* s = w_out + (size_t)idx * 8;
    *(uint4*)(w_out_bf + (size_t)idx * 8) = pack8(*(const float4*)s, *(const float4*)(s + 4));
}

// ---------- GEMM (m97-style): Out[m,n] = sum_k A[m,k]*Bw[n,k] (+resid). bf16 in, global_load_lds staging ----------
// M fixed 8192 (64 m-tiles). grid = 64*NT, 1D. XCD swizzle: m confined per XCD.
template <bool OUT_F32, bool RESID>
__global__ __launch_bounds__(256)
void gemm_lds(const unsigned short* __restrict__ A, const unsigned short* __restrict__ Bw,
              void* __restrict__ Outp, const float* __restrict__ Resid,
              int NT, int N_real, int K, int lda) {
    __shared__ __align__(16) __bf16 As[128 * 32];
    __shared__ __align__(16) __bf16 Bs[128 * 32];

    const int tid = threadIdx.x;
    const int blk = blockIdx.x;
    const int xcd = blk & 7, j = blk >> 3;
    const int m0 = (xcd * 8 + (j & 7)) * 128;      // 8 m-tiles per XCD -> A L2-resident
    const int n0 = (j >> 3) * 128;

    const int wave = tid >> 6, lane = tid & 63;
    const int wm = (wave & 1) * 64, wn = (wave >> 1) * 64;
    const int lr = lane & 15, q = lane >> 4;

    const int srow = tid >> 2;                     // 0..63
    const int scol = (tid & 3) << 3;               // 0,8,16,24
    const unsigned short* ag  = A + (size_t)(m0 + srow) * lda + scol;
    const unsigned short* ag2 = A + (size_t)(m0 + 64 + srow) * lda + scol;
    const unsigned short* bg  = Bw + (size_t)(n0 + srow) * K + scol;
    const unsigned short* bg2 = Bw + (size_t)(n0 + 64 + srow) * K + scol;
    __bf16* asd  = As + tid * 8;                   // LDS byte off = tid*16 (wave-uniform + lane*16)
    __bf16* asd2 = As + 2048 + tid * 8;
    __bf16* bsd  = Bs + tid * 8;
    __bf16* bsd2 = Bs + 2048 + tid * 8;

    f32x4 acc[4][4] = {};

    for (int k0 = 0; k0 < K; k0 += 32) {
        load_lds16(ag + k0, asd);
        load_lds16(ag2 + k0, asd2);
        load_lds16(bg + k0, bsd);
        load_lds16(bg2 + k0, bsd2);
        __syncthreads();

        bf16x8 af[4], bfr[4];
        #pragma unroll
        for (int t = 0; t < 4; ++t) {
            af[t]  = *(const bf16x8*)(As + (wm + t * 16 + lr) * 32 + q * 8);
            bfr[t] = *(const bf16x8*)(Bs + (wn + t * 16 + lr) * 32 + q * 8);
        }
        #pragma unroll
        for (int ti = 0; ti < 4; ++ti)
            #pragma unroll
            for (int tj = 0; tj < 4; ++tj)
                acc[ti][tj] = __builtin_amdgcn_mfma_f32_16x16x32_bf16(af[ti], bfr[tj], acc[ti][tj], 0, 0, 0);
        __syncthreads();
    }

    #pragma unroll
    for (int ti = 0; ti < 4; ++ti) {
        #pragma unroll
        for (int r = 0; r < 4; ++r) {
            int m = m0 + wm + ti * 16 + q * 4 + r;
            #pragma unroll
            for (int tj = 0; tj < 4; ++tj) {
                int n = n0 + wn + tj * 16 + lr;
                if (n < N_real) {
                    float v = acc[ti][tj][r];
                    if (RESID) v += Resid[(size_t)m * N_real + n];
                    if (OUT_F32) ((float*)Outp)[(size_t)m * N_real + n] = v;
                    else ((unsigned short*)Outp)[(size_t)m * N_real + n] = f2bf(v);
                }
            }
        }
    }
}

// ---------- causal depthwise conv(4) + silu, 8 channels/thread ----------
__global__ __launch_bounds__(256)
void conv_silu_kernel(const unsigned short* __restrict__ zx,
                      const float* __restrict__ cw,
                      const float* __restrict__ cb,
                      float* __restrict__ convo) {
    int idx = blockIdx.x * 256 + threadIdx.x;
    if (idx >= 8192 * 224) return;
    int c8 = idx % 224;
    int row = idx / 224;
    int c = c8 << 3;
    int l = row & 2047;                     // L = 2048
    float acc[8];
    #pragma unroll
    for (int i = 0; i < 8; ++i) acc[i] = cb[c + i];
    #pragma unroll
    for (int k = 0; k < 4; ++k) {
        int dl = 3 - k;
        if (l >= dl) {
            const unsigned short* src = zx + (size_t)(row - dl) * 3352 + 1536 + c;
            uint4 v = *(const uint4*)src;
            unsigned short uu[8];
            uu[0] = v.x & 0xFFFF; uu[1] = v.x >> 16;
            uu[2] = v.y & 0xFFFF; uu[3] = v.y >> 16;
            uu[4] = v.z & 0xFFFF; uu[5] = v.z >> 16;
            uu[6] = v.w & 0xFFFF; uu[7] = v.w >> 16;
            #pragma unroll
            for (int i = 0; i < 8; ++i) acc[i] += bf2f(uu[i]) * cw[(c + i) * 4 + k];
        }
    }
    float* dst = convo + (size_t)row * 1792 + c;
    #pragma unroll
    for (int i = 0; i < 8; ++i) { float a = acc[i]; dst[i] = a / (1.f + expf(-a)); }
}

// ---------- dt in full f32 -> interleaved (dt, dt*A) float2 ----------
__global__ __launch_bounds__(64)
void dt_kernel(const float* __restrict__ x, const float* __restrict__ w_in,
               const float* __restrict__ dt_bias, const float* __restrict__ A_log,
               float2* __restrict__ dtdA) {
    int row = blockIdx.x;
    int lane = threadIdx.x;
    float xv[12];
    #pragma unroll
    for (int i = 0; i < 12; ++i) xv[i] = x[(size_t)row * 768 + i * 64 + lane];
    for (int h = 0; h < 24; ++h) {
        const float* w = w_in + (size_t)(3328 + h) * 768;
        float acc = 0.f;
        #pragma unroll
        for (int i = 0; i < 12; ++i) acc += xv[i] * w[i * 64 + lane];
        #pragma unroll
        for (int m = 1; m < 64; m <<= 1) acc += __shfl_xor(acc, m);
        if (lane == 0) {
            float v = acc + dt_bias[h];
            float dt = (v > 20.f) ? v : log1pf(expf(v));
            float A = -expf(A_log[h]);
            dtdA[(size_t)row * 24 + h] = make_float2(dt, dt * A);   // (dt, log dA)
        }
    }
}

// ---------- tiled transpose: cv (f32 [row][ch]) -> xT/bT (bf16 [ch][t]) ----------
__global__ __launch_bounds__(256)
void transpose_kernel(const float* __restrict__ cv,
                      unsigned short* __restrict__ xT,
                      unsigned short* __restrict__ bT) {
    __shared__ __bf16 tile[64][74];
    int blk = blockIdx.x;
    int tt  = blk & 31;
    int cht = (blk >> 5) % 26;
    int b   = blk / (32 * 26);
    int ch0 = cht * 64, t0 = tt * 64;
    int tx = threadIdx.x & 63, ty4 = threadIdx.x >> 6;

    const float* src = cv + ((size_t)(b * 2048 + t0)) * 1792 + ch0;
    #pragma unroll
    for (int k = 0; k < 16; ++k) {
        int i = ty4 * 16 + k;
        float v = src[(size_t)i * 1792 + tx];
        unsigned short u = f2bf(v);
        tile[i][tx] = *(__bf16*)&u;
    }
    __syncthreads();
    #pragma unroll
    for (int k = 0; k < 16; ++k) {
        int chl = ty4 * 16 + k;
        __bf16 bv = tile[tx][chl];
        unsigned short u = *(unsigned short*)&bv;
        int ch = ch0 + chl;
        if (ch < 1536)
            xT[((size_t)(b * 1536 + ch)) * 2048 + t0 + tx] = u;
        else
            bT[((size_t)(b * 128 + ch - 1536)) * 2048 + t0 + tx] = u;
    }
}

// ---------- SSD local kernel: per (b,h,chunk): G -> M -> Y, s_out ----------
__global__ __launch_bounds__(256)
void ssd_local_kernel(const float* __restrict__ cv,
                      const float2* __restrict__ dtdA,
                      const unsigned short* __restrict__ xT,
                      const unsigned short* __restrict__ bT,
                      const float* __restrict__ Dh,
                      float* __restrict__ yb,
                      unsigned short* __restrict__ sst,
                      float* __restrict__ Pbuf) {
    extern __shared__ __align__(16) char smem[];
    __bf16* Bs  = (__bf16*)smem;                 // 128 x SLD; later Xt(0:17408)+Xtw(17408:34816)
    __bf16* Cs  = (__bf16*)(smem + 34816);       // 128 x SLD; later Ms
    float*  Lc  = (float*)(smem + 69632);        // 128
    float*  dtl = (float*)(smem + 70144);        // 128

    const int tid = threadIdx.x;
    const int c   = blockIdx.x & 15;
    const int bh  = blockIdx.x >> 4;
    const int b   = bh / 24, h = bh % 24;
    const int t0g = b * 2048 + c * QCHUNK;
    const int wave = tid >> 6, lane = tid & 63;
    const int lr = lane & 15, q = lane >> 4;

    const float* cvb = cv + (size_t)t0g * 1792;
    for (int cc = tid; cc < 2048; cc += 256) {
        int r = cc >> 4, c8 = (cc & 15) << 3;
        const float* sB = cvb + (size_t)r * 1792 + 1536 + c8;
        *(uint4*)(Bs + r * SLD + c8) = pack8(*(const float4*)sB, *(const float4*)(sB + 4));
        const float* sC = cvb + (size_t)r * 1792 + 1664 + c8;
        *(uint4*)(Cs + r * SLD + c8) = pack8(*(const float4*)sC, *(const float4*)(sC + 4));
    }
    if (tid < 128) {
        float2 dd = dtdA[((size_t)t0g + tid) * 24 + h];
        dtl[tid] = dd.x;
        Lc[tid]  = dd.y;     // log dA
    }
    __syncthreads();
    for (int off = 1; off < 128; off <<= 1) {
        float v = 0.f;
        if (tid < 128 && tid >= off) v = Lc[tid - off];
        __syncthreads();
        if (tid < 128) Lc[tid] += v;
        __syncthreads();
    }

    // P1: G = Cs . Bs^T
    const int wm = (wave & 1) * 64, wn = (wave >> 1) * 64;
    f32x4 g[4][4] = {};
    #pragma unroll
    for (int k0 = 0; k0 < 128; k0 += 32) {
        bf16x8 af[4], bfr[4];
        #pragma unroll
        for (int t = 0; t < 4; ++t) {
            af[t]  = *(const bf16x8*)(Cs + (wm + t * 16 + lr) * SLD + k0 + q * 8);
            bfr[t] = *(const bf16x8*)(Bs + (wn + t * 16 + lr) * SLD + k0 + q * 8);
        }
        #pragma unroll
        for (int ti = 0; ti < 4; ++ti)
            #pragma unroll
            for (int tj = 0; tj < 4; ++tj)
                g[ti][tj] = __builtin_amdgcn_mfma_f32_16x16x32_bf16(af[ti], bfr[tj], g[ti][tj], 0, 0, 0);
    }
    __syncthreads();

    // P5: masked scale -> Ms[t][tau]
    __bf16* Ms = Cs;
    {
        float lt_[4], dt_[4];
        #pragma unroll
        for (int tj = 0; tj < 4; ++tj) {
            int tau = wn + tj * 16 + lr;
            lt_[tj] = Lc[tau];
            dt_[tj] = dtl[tau];
        }
        #pragma unroll
        for (int ti = 0; ti < 4; ++ti) {
            #pragma unroll
            for (int r = 0; r < 4; ++r) {
                int t = wm + ti * 16 + q * 4 + r;
                float Lt = Lc[t];
                #pragma unroll
                for (int tj = 0; tj < 4; ++tj) {
                    int tau = wn + tj * 16 + lr;
                    float mv = (tau <= t) ? g[ti][tj][r] * expf(Lt - lt_[tj]) * dt_[tj] : 0.f;
                    unsigned short u = f2bf(mv);
                    Ms[t * SLD + tau] = *(__bf16*)&u;
                }
            }
        }
    }

    // P3: stage Xt[p][t] and Xtw[p][t]
    __bf16* Xt  = Bs;
    __bf16* Xtw = (__bf16*)(smem + 17408);
    {
        float LQ = Lc[127];
        const unsigned short* xTb = xT + ((size_t)(b * 1536 + h * 64)) * 2048 + c * QCHUNK;
        for (int cc = tid; cc < 1024; cc += 256) {
            int p = cc >> 4, c8 = (cc & 15) << 3;
            uint4 v = *(const uint4*)(xTb + (size_t)p * 2048 + c8);
            *(uint4*)(Xt + p * SLD + c8) = v;
            unsigned short uu[8] = {(unsigned short)(v.x & 0xFFFF), (unsigned short)(v.x >> 16),
                                    (unsigned short)(v.y & 0xFFFF), (unsigned short)(v.y >> 16),
                                    (unsigned short)(v.z & 0xFFFF), (unsigned short)(v.z >> 16),
                                    (unsigned short)(v.w & 0xFFFF), (unsigned short)(v.w >> 16)};
            float w0[8];
            #pragma unroll
            for (int jj = 0; jj < 8; ++jj) {
                int tau = c8 + jj;
                w0[jj] = bf2f(uu[jj]) * expf(LQ - Lc[tau]) * dtl[tau];
            }
            *(uint4*)(Xtw + p * SLD + c8) = pack8(make_float4(w0[0], w0[1], w0[2], w0[3]),
                                                  make_float4(w0[4], w0[5], w0[6], w0[7]));
        }
    }
    __syncthreads();

    // P4: s_out[n][p] = bT . Xtw^T
    {
        f32x4 so[2][4] = {};
        const unsigned short* bTb = bT + ((size_t)(b * 128)) * 2048 + c * QCHUNK;
        #pragma unroll
        for (int k0 = 0; k0 < 128; k0 += 32) {
            bf16x8 af[2], bfr[4];
            #pragma unroll
            for (int ti = 0; ti < 2; ++ti) {
                int n = wave * 32 + ti * 16 + lr;
                af[ti] = *(const bf16x8*)(bTb + (size_t)n * 2048 + k0 + q * 8);
            }
            #pragma unroll
            for (int tj = 0; tj < 4; ++tj)
                bfr[tj] = *(const bf16x8*)(Xtw + (tj * 16 + lr) * SLD + k0 + q * 8);
            #pragma unroll
            for (int ti = 0; ti < 2; ++ti)
                #pragma unroll
                for (int tj = 0; tj < 4; ++tj)
                    so[ti][tj] = __builtin_amdgcn_mfma_f32_16x16x32_bf16(af[ti], bfr[tj], so[ti][tj], 0, 0, 0);
        }
        unsigned short* sb = sst + ((size_t)(bh * NCHUNK + c)) * 8192;
        #pragma unroll
        for (int ti = 0; ti < 2; ++ti) {
            #pragma unroll
            for (int r = 0; r < 4; ++r) {
                int n = wave * 32 + ti * 16 + q * 4 + r;
                #pragma unroll
                for (int tj = 0; tj < 4; ++tj) {
                    int p = tj * 16 + lr;
                    sb[n * 64 + p] = f2bf(so[ti][tj][r]);
                }
            }
        }
        if (tid == 0) Pbuf[bh * NCHUNK + c] = expf(Lc[127]);
    }

    // P6: Y[t][p] = Ms . Xt^T  (+ D skip)
    {
        f32x4 ya[2][4] = {};
        #pragma unroll
        for (int k0 = 0; k0 < 128; k0 += 32) {
            bf16x8 af[2], bfr[4];
            #pragma unroll
            for (int ti = 0; ti < 2; ++ti)
                af[ti] = *(const bf16x8*)(Ms + (wave * 32 + ti * 16 + lr) * SLD + k0 + q * 8);
            #pragma unroll
            for (int tj = 0; tj < 4; ++tj)
                bfr[tj] = *(const bf16x8*)(Xt + (tj * 16 + lr) * SLD + k0 + q * 8);
            #pragma unroll
            for (int ti = 0; ti < 2; ++ti)
                #pragma unroll
                for (int tj = 0; tj < 4; ++tj)
                    ya[ti][tj] = __builtin_amdgcn_mfma_f32_16x16x32_bf16(af[ti], bfr[tj], ya[ti][tj], 0, 0, 0);
        }
        float Dv = Dh[h];
        float* ybb = yb + (size_t)t0g * 1536 + h * 64;
        #pragma unroll
        for (int ti = 0; ti < 2; ++ti) {
            #pragma unroll
            for (int r = 0; r < 4; ++r) {
                int t = wave * 32 + ti * 16 + q * 4 + r;
                #pragma unroll
                for (int tj = 0; tj < 4; ++tj) {
                    int p = tj * 16 + lr;
                    __bf16 xb = Xt[p * SLD + t];
                    float xv = bf2f(*(unsigned short*)&xb);
                    ybb[(size_t)t * 1536 + p] = ya[ti][tj][r] + Dv * xv;
                }
            }
        }
    }
}

// ---------- combine ----------
__global__ __launch_bounds__(256)
void combine_kernel(const unsigned short* __restrict__ sst,
                    unsigned short* __restrict__ sstT,
                    const float* __restrict__ Pbuf) {
    int flat = blockIdx.x * 256 + threadIdx.x;
    int bh = flat >> 13;
    int pn = flat & 8191;
    int n = pn >> 6, p = pn & 63;
    const unsigned short* sb = sst + (size_t)bh * NCHUNK * 8192;
    unsigned short* tb = sstT + (size_t)bh * NCHUNK * 8192 + p * 128 + n;
    const float* Pb = Pbuf + bh * NCHUNK;
    float s = 0.f;
    #pragma unroll
    for (int c = 0; c < NCHUNK; ++c) {
        float tmp = bf2f(sb[(size_t)c * 8192 + pn]);
        tb[(size_t)c * 8192] = f2bf(s);
        s = Pb[c] * s + tmp;
    }
}

// ---------- SSD inter kernel ----------
__global__ __launch_bounds__(256)
void ssd_inter_kernel(const float* __restrict__ cv,
                      const float2* __restrict__ dtdA,
                      const unsigned short* __restrict__ sstT,
                      float* __restrict__ yb) {
    __shared__ __align__(16) __bf16 Cs[128 * SLD];
    __shared__ __align__(16) __bf16 St[64 * SLD];
    __shared__ float Lc[128];

    const int tid = threadIdx.x;
    const int blk = blockIdx.x;
    const int bh = blk / 15;
    const int c  = blk % 15 + 1;
    const int b = bh / 24, h = bh % 24;
    const int t0g = b * 2048 + c * QCHUNK;
    const int wave = tid >> 6, lane = tid & 63;
    const int lr = lane & 15, q = lane >> 4;

    const float* cvb = cv + (size_t)t0g * 1792;
    for (int cc = tid; cc < 2048; cc += 256) {
        int r = cc >> 4, c8 = (cc & 15) << 3;
        const float* sC = cvb + (size_t)r * 1792 + 1664 + c8;
        *(uint4*)(Cs + r * SLD + c8) = pack8(*(const float4*)sC, *(const float4*)(sC + 4));
    }
    const unsigned short* stb = sstT + ((size_t)(bh * NCHUNK + c)) * 8192;
    for (int cc = tid; cc < 1024; cc += 256) {
        int p = cc >> 4, c8 = (cc & 15) << 3;
        *(uint4*)(St + p * SLD + c8) = *(const uint4*)(stb + p * 128 + c8);
    }
    if (tid < 128) Lc[tid] = dtdA[((size_t)t0g + tid) * 24 + h].y;
    __syncthreads();
    for (int off = 1; off < 128; off <<= 1) {
        float v = 0.f;
        if (tid < 128 && tid >= off) v = Lc[tid - off];
        __syncthreads();
        if (tid < 128) Lc[tid] += v;
        __syncthreads();
    }

    f32x4 ya[2][4] = {};
    #pragma unroll
    for (int k0 = 0; k0 < 128; k0 += 32) {
        bf16x8 af[2], bfr[4];
        #pragma unroll
        for (int ti = 0; ti < 2; ++ti)
            af[ti] = *(const bf16x8*)(Cs + (wave * 32 + ti * 16 + lr) * SLD + k0 + q * 8);
        #pragma unroll
        for (int tj = 0; tj < 4; ++tj)
            bfr[tj] = *(const bf16x8*)(St + (tj * 16 + lr) * SLD + k0 + q * 8);
        #pragma unroll
        for (int ti = 0; ti < 2; ++ti)
            #pragma unroll
            for (int tj = 0; tj < 4; ++tj)
                ya[ti][tj] = __builtin_amdgcn_mfma_f32_16x16x32_bf16(af[ti], bfr[tj], ya[ti][tj], 0, 0, 0);
    }
    float* ybb = yb + (size_t)t0g * 1536 + h * 64;
    #pragma unroll
    for (int ti = 0; ti < 2; ++ti) {
        #pragma unroll
        for (int r = 0; r < 4; ++r) {
            int t = wave * 32 + ti * 16 + q * 4 + r;
            float sc = expf(Lc[t]);
            #pragma unroll
            for (int tj = 0; tj < 4; ++tj) {
                int p = tj * 16 + lr;
                float* yp = ybb + (size_t)t * 1536 + p;
                *yp = *yp + sc * ya[ti][tj][r];
            }
        }
    }
}

// ---------- gated RMSNorm: writes bf16 into zx cols [1536,3072) ----------
__global__ __launch_bounds__(256)
void norm_kernel(const float* __restrict__ yb,
                 unsigned short* __restrict__ zx,
                 const float* __restrict__ nw) {
    int row = blockIdx.x;
    const float* yr = yb + (size_t)row * 1536;
    unsigned short* zr = zx + (size_t)row * 3352;
    int tid = threadIdx.x;
    float u[6];
    float ss = 0.f;
    #pragma unroll
    for (int i = 0; i < 6; ++i) {
        int c = tid + i * 256;
        float z = bf2f(zr[c]);
        float uu = yr[c] * (z / (1.f + expf(-z)));
        u[i] = uu;
        ss += uu * uu;
    }
    #pragma unroll
    for (int m = 1; m < 64; m <<= 1) ss += __shfl_xor(ss, m);
    __shared__ float red[4];
    if ((tid & 63) == 0) red[tid >> 6] = ss;
    __syncthreads();
    float tot = red[0] + red[1] + red[2] + red[3];
    float inv = rsqrtf(tot * (1.f / 1536.f) + 1e-5f);
    #pragma unroll
    for (int i = 0; i < 6; ++i) {
        int c = tid + i * 256;
        zr[1536 + c] = f2bf(u[i] * inv * nw[c]);
    }
}

// ---------- launch ----------
extern "C" void kernel_launch(void* const* d_in, const int* in_sizes, int n_in,
                              void* d_out, int out_size, void* d_ws, size_t ws_size,
                              hipStream_t stream) {
    const float* x       = (const float*)d_in[0];
    const float* w_in    = (const float*)d_in[1];
    const float* conv_w  = (const float*)d_in[2];
    const float* conv_b  = (const float*)d_in[3];
    const float* dt_bias = (const float*)d_in[4];
    const float* A_log   = (const float*)d_in[5];
    const float* Dp      = (const float*)d_in[6];
    const float* nw      = (const float*)d_in[7];
    const float* w_out   = (const float*)d_in[8];
    float* out = (float*)d_out;

    char* ws = (char*)d_ws;
    const size_t off_zx   = 0;                        // 8192*3352 bf16 = 54,919,168
    const size_t off_conv = off_zx + 54919168;        // 8192*1792 f32  = 58,720,256
    const size_t off_dtdA = off_conv + 58720256;      // 1,572,864
    const size_t off_y    = off_dtdA + 1572864;       // 50,331,648  (x_bf aliases head: 12.6 MB)
    const size_t off_sst  = off_y + 50331648;         // 25,165,824  (w_in_bf aliases head: 5.3 MB)
    const size_t off_xT   = off_sst + 25165824;       // 25,165,824 (sstT alias)
    const size_t off_bT   = off_xT + 25165824;        // 2,097,152
    const size_t off_P    = off_bT + 2097152;         // 6,144

    unsigned short* zx  = (unsigned short*)(ws + off_zx);
    float* cv    = (float*)(ws + off_conv);
    float2* dtdA = (float2*)(ws + off_dtdA);
    float* yb    = (float*)(ws + off_y);
    unsigned short* sst  = (unsigned short*)(ws + off_sst);
    unsigned short* xT   = (unsigned short*)(ws + off_xT);
    unsigned short* sstT = xT;
    unsigned short* bT   = (unsigned short*)(ws + off_bT);
    float* Pbuf = (float*)(ws + off_P);

    // transient aliases (dead regions at time of use)
    unsigned short* x_bf    = (unsigned short*)(ws + off_y);     // used only by gemm1 (before yb written)
    unsigned short* w_in_bf = (unsigned short*)(ws + off_sst);   // used only by gemm1 (before sst written)
    unsigned short* w_out_bf= (unsigned short*)(ws + off_conv);  // written after cv dead, used by gemm2

    static bool attr_set = false;
    if (!attr_set) {
        hipFuncSetAttribute((const void*)ssd_local_kernel,
                            hipFuncAttributeMaxDynamicSharedMemorySize, 70656);
        attr_set = true;
    }

    // 0. convert x, w_in (padded to 3456 rows) -> bf16
    convert_kernel<<<4368, 256, 0, stream>>>(x, w_in, x_bf, w_in_bf);
    // 1. in_proj (M=8192, N=3352->3456 padded, K=768), bf16 in -> bf16 out, guarded store ld=3352
    gemm_lds<false, false><<<64 * 27, 256, 0, stream>>>(x_bf, w_in_bf, zx, nullptr, 27, 3352, 768, 768);
    // 2. conv + silu
    conv_silu_kernel<<<7168, 256, 0, stream>>>(zx, conv_w, conv_b, cv);
    // 3. dt / log-dA (full f32)
    dt_kernel<<<8192, 64, 0, stream>>>(x, w_in, dt_bias, A_log, dtdA);
    // 4. transpose x/B regions of cv -> xT, bT
    transpose_kernel<<<3328, 256, 0, stream>>>(cv, xT, bT);
    // 5. SSD local
    ssd_local_kernel<<<1536, 256, 70656, stream>>>(cv, dtdA, xT, bT, Dp, yb, sst, Pbuf);
    // 6. combine
    combine_kernel<<<3072, 256, 0, stream>>>(sst, sstT, Pbuf);
    // 7. SSD inter
    ssd_inter_kernel<<<1440, 256, 0, stream>>>(cv, dtdA, sstT, yb);
    // 7.5 convert w_out -> bf16 (cv region is dead now)
    convert_wout_kernel<<<576, 256, 0, stream>>>(w_out, w_out_bf);
    // 8. gated RMSNorm -> bf16 into zx cols [1536,3072)
    norm_kernel<<<8192, 256, 0, stream>>>(yb, zx, nw);
    // 9. out_proj + residual (A = normed y in zx, lda=3352; B = w_out_bf, K=1536)
    gemm_lds<true, true><<<64 * 6, 256, 0, stream>>>(zx + 1536, w_out_bf, out, x, 6, 768, 1536, 3352);
}

// Round 7
// 455.379 us; speedup vs baseline: 2.7538x; 1.2412x over previous
//
#include <hip/hip_runtime.h>
#include <math.h>

// ---------- types ----------
typedef __bf16 bf16x8 __attribute__((ext_vector_type(8)));
typedef float  f32x4  __attribute__((ext_vector_type(4)));

#define QCHUNK 128
#define NCHUNK 16
#define SLD 136              // LDS row stride (bf16 elems) for 128-wide arrays

__device__ __forceinline__ float bf2f(unsigned short u) {
    union { unsigned int i; float f; } v; v.i = ((unsigned int)u) << 16; return v.f;
}
__device__ __forceinline__ unsigned short f2bf(float f) {
    union { float f; unsigned int i; } v; v.f = f;
    unsigned int x = v.i;
    unsigned int r = (x + 0x7FFFu + ((x >> 16) & 1u)) >> 16;
    return (unsigned short)r;
}
__device__ __forceinline__ uint4 pack8(float4 a, float4 b) {
    uint4 r;
    r.x = (unsigned)f2bf(a.x) | ((unsigned)f2bf(a.y) << 16);
    r.y = (unsigned)f2bf(a.z) | ((unsigned)f2bf(a.w) << 16);
    r.z = (unsigned)f2bf(b.x) | ((unsigned)f2bf(b.y) << 16);
    r.w = (unsigned)f2bf(b.z) | ((unsigned)f2bf(b.w) << 16);
    return r;
}
__device__ __forceinline__ void load_lds16(const void* g, void* l) {
    __builtin_amdgcn_global_load_lds((const __attribute__((address_space(1))) void*)g,
                                     (__attribute__((address_space(3))) void*)l,
                                     16, 0, 0);
}

// ---------- convert: x -> x_bf, w_in -> w_in_bf (padded 3456 rows, zero-filled) ----------
__global__ __launch_bounds__(256)
void convert_kernel(const float* __restrict__ x, const float* __restrict__ w_in,
                    unsigned short* __restrict__ x_bf, unsigned short* __restrict__ w_in_bf) {
    int idx = blockIdx.x * 256 + threadIdx.x;      // 8 elems each
    const int NX  = 8192 * 768 / 8;                // 786432
    const int NW1 = 3456 * 768 / 8;                // 331776 (padded)
    const int NW1r = 3352 * 768 / 8;               // 321792 (real)
    if (idx < NX) {
        const float* s = x + (size_t)idx * 8;
        *(uint4*)(x_bf + (size_t)idx * 8) = pack8(*(const float4*)s, *(const float4*)(s + 4));
    } else if (idx < NX + NW1) {
        int j = idx - NX;
        uint4 v = make_uint4(0u, 0u, 0u, 0u);
        if (j < NW1r) {
            const float* s = w_in + (size_t)j * 8;
            v = pack8(*(const float4*)s, *(const float4*)(s + 4));
        }
        *(uint4*)(w_in_bf + (size_t)j * 8) = v;
    }
}

// ---------- convert w_out -> bf16 ----------
__global__ __launch_bounds__(256)
void convert_wout_kernel(const float* __restrict__ w_out, unsigned short* __restrict__ w_out_bf) {
    int idx = blockIdx.x * 256 + threadIdx.x;      // 147456 total
    const float* s = w_out + (size_t)idx * 8;
    *(uint4*)(w_out_bf + (size_t)idx * 8) = pack8(*(const float4*)s, *(const float4*)(s + 4));
}

// ---------- GEMM (m97-style): Out[m,n] = sum_k A[m,k]*Bw[n,k] (+resid). bf16 in, global_load_lds staging ----------
template <bool OUT_F32, bool RESID>
__global__ __launch_bounds__(256)
void gemm_lds(const unsigned short* __restrict__ A, const unsigned short* __restrict__ Bw,
              void* __restrict__ Outp, const float* __restrict__ Resid,
              int NT, int N_real, int K, int lda) {
    __shared__ __align__(16) __bf16 As[128 * 32];
    __shared__ __align__(16) __bf16 Bs[128 * 32];

    const int tid = threadIdx.x;
    const int blk = blockIdx.x;
    const int xcd = blk & 7, j = blk >> 3;
    const int m0 = (xcd * 8 + (j & 7)) * 128;
    const int n0 = (j >> 3) * 128;

    const int wave = tid >> 6, lane = tid & 63;
    const int wm = (wave & 1) * 64, wn = (wave >> 1) * 64;
    const int lr = lane & 15, q = lane >> 4;

    const int srow = tid >> 2;
    const int scol = (tid & 3) << 3;
    const unsigned short* ag  = A + (size_t)(m0 + srow) * lda + scol;
    const unsigned short* ag2 = A + (size_t)(m0 + 64 + srow) * lda + scol;
    const unsigned short* bg  = Bw + (size_t)(n0 + srow) * K + scol;
    const unsigned short* bg2 = Bw + (size_t)(n0 + 64 + srow) * K + scol;
    __bf16* asd  = As + tid * 8;
    __bf16* asd2 = As + 2048 + tid * 8;
    __bf16* bsd  = Bs + tid * 8;
    __bf16* bsd2 = Bs + 2048 + tid * 8;

    f32x4 acc[4][4] = {};

    for (int k0 = 0; k0 < K; k0 += 32) {
        load_lds16(ag + k0, asd);
        load_lds16(ag2 + k0, asd2);
        load_lds16(bg + k0, bsd);
        load_lds16(bg2 + k0, bsd2);
        __syncthreads();

        bf16x8 af[4], bfr[4];
        #pragma unroll
        for (int t = 0; t < 4; ++t) {
            af[t]  = *(const bf16x8*)(As + (wm + t * 16 + lr) * 32 + q * 8);
            bfr[t] = *(const bf16x8*)(Bs + (wn + t * 16 + lr) * 32 + q * 8);
        }
        #pragma unroll
        for (int ti = 0; ti < 4; ++ti)
            #pragma unroll
            for (int tj = 0; tj < 4; ++tj)
                acc[ti][tj] = __builtin_amdgcn_mfma_f32_16x16x32_bf16(af[ti], bfr[tj], acc[ti][tj], 0, 0, 0);
        __syncthreads();
    }

    #pragma unroll
    for (int ti = 0; ti < 4; ++ti) {
        #pragma unroll
        for (int r = 0; r < 4; ++r) {
            int m = m0 + wm + ti * 16 + q * 4 + r;
            #pragma unroll
            for (int tj = 0; tj < 4; ++tj) {
                int n = n0 + wn + tj * 16 + lr;
                if (n < N_real) {
                    float v = acc[ti][tj][r];
                    if (RESID) v += Resid[(size_t)m * N_real + n];
                    if (OUT_F32) ((float*)Outp)[(size_t)m * N_real + n] = v;
                    else ((unsigned short*)Outp)[(size_t)m * N_real + n] = f2bf(v);
                }
            }
        }
    }
}

// ---------- fused conv(4)+silu+layout: zx xBC cols -> xT (transposed), bT (transposed), Brow/Crow (row-major), all bf16 ----------
// grid: b(4) x t-tile(32) x ch-tile(28), 256 threads. Tile 64 t x 64 ch.
__global__ __launch_bounds__(256)
void conv_fused_kernel(const unsigned short* __restrict__ zx,
                       const float* __restrict__ cw, const float* __restrict__ cb,
                       unsigned short* __restrict__ xT, unsigned short* __restrict__ bT,
                       unsigned short* __restrict__ Brow, unsigned short* __restrict__ Crow) {
    __shared__ unsigned short outt[64][66];
    __shared__ float cwl[64][4];
    __shared__ float cbl[64];

    int blk = blockIdx.x;
    int cht = blk % 28;
    int tt  = (blk / 28) % 32;
    int b   = blk / (28 * 32);
    int ch0 = cht * 64, t0 = tt * 64;
    int tid = threadIdx.x;
    int tx = tid & 63, ty = tid >> 6;

    if (tid < 64) cbl[tid] = cb[ch0 + tid];
    cwl[tid >> 2][tid & 3] = cw[(ch0 + (tid >> 2)) * 4 + (tid & 3)];
    __syncthreads();

    const unsigned short* zp = zx + (size_t)(b * 2048) * 3352 + 1536 + ch0 + tx;
    float w0 = cwl[tx][0], w1 = cwl[tx][1], w2 = cwl[tx][2], w3 = cwl[tx][3];
    float bias = cbl[tx];
    int tg = t0 + ty * 16;                 // first output t for this thread
    float r0 = (tg >= 3) ? bf2f(zp[(size_t)(tg - 3) * 3352]) : 0.f;
    float r1 = (tg >= 2) ? bf2f(zp[(size_t)(tg - 2) * 3352]) : 0.f;
    float r2 = (tg >= 1) ? bf2f(zp[(size_t)(tg - 1) * 3352]) : 0.f;
    #pragma unroll
    for (int k = 0; k < 16; ++k) {
        float cur = bf2f(zp[(size_t)(tg + k) * 3352]);
        float a = bias + r0 * w0 + r1 * w1 + r2 * w2 + cur * w3;
        a = a / (1.f + expf(-a));          // silu
        outt[ty * 16 + k][tx] = f2bf(a);
        r0 = r1; r1 = r2; r2 = cur;
    }
    __syncthreads();

    if (ch0 < 1536) {
        // x region: transposed write xT[ch][t]
        unsigned short* dst = xT + ((size_t)(b * 1536 + ch0)) * 2048 + t0;
        #pragma unroll
        for (int k = 0; k < 16; ++k) {
            int chl = ty * 16 + k;
            dst[(size_t)chl * 2048 + tx] = outt[tx][chl];
        }
    } else if (ch0 < 1664) {
        // B region: transposed bT[n][t] + row-major Brow[t][n]
        int n0 = ch0 - 1536;
        unsigned short* dstT = bT + ((size_t)(b * 128 + n0)) * 2048 + t0;
        #pragma unroll
        for (int k = 0; k < 16; ++k) {
            int chl = ty * 16 + k;
            dstT[(size_t)chl * 2048 + tx] = outt[tx][chl];
        }
        unsigned short* dstR = Brow + ((size_t)(b * 2048 + t0)) * 128 + n0;
        int tl = tid >> 3, c8 = (tid & 7) << 3;
        #pragma unroll
        for (int it = 0; it < 2; ++it) {
            int t = tl + it * 32;
            unsigned short tmp[8];
            #pragma unroll
            for (int jj = 0; jj < 8; ++jj) tmp[jj] = outt[t][c8 + jj];
            *(uint4*)(dstR + (size_t)t * 128 + c8) = *(uint4*)tmp;
        }
    } else {
        // C region: row-major Crow[t][n]
        int n0 = ch0 - 1664;
        unsigned short* dstR = Crow + ((size_t)(b * 2048 + t0)) * 128 + n0;
        int tl = tid >> 3, c8 = (tid & 7) << 3;
        #pragma unroll
        for (int it = 0; it < 2; ++it) {
            int t = tl + it * 32;
            unsigned short tmp[8];
            #pragma unroll
            for (int jj = 0; jj < 8; ++jj) tmp[jj] = outt[t][c8 + jj];
            *(uint4*)(dstR + (size_t)t * 128 + c8) = *(uint4*)tmp;
        }
    }
}

// ---------- dt in full f32 -> interleaved (dt, dt*A) float2 ----------
__global__ __launch_bounds__(64)
void dt_kernel(const float* __restrict__ x, const float* __restrict__ w_in,
               const float* __restrict__ dt_bias, const float* __restrict__ A_log,
               float2* __restrict__ dtdA) {
    int row = blockIdx.x;
    int lane = threadIdx.x;
    float xv[12];
    #pragma unroll
    for (int i = 0; i < 12; ++i) xv[i] = x[(size_t)row * 768 + i * 64 + lane];
    for (int h = 0; h < 24; ++h) {
        const float* w = w_in + (size_t)(3328 + h) * 768;
        float acc = 0.f;
        #pragma unroll
        for (int i = 0; i < 12; ++i) acc += xv[i] * w[i * 64 + lane];
        #pragma unroll
        for (int m = 1; m < 64; m <<= 1) acc += __shfl_xor(acc, m);
        if (lane == 0) {
            float v = acc + dt_bias[h];
            float dt = (v > 20.f) ? v : log1pf(expf(v));
            float A = -expf(A_log[h]);
            dtdA[(size_t)row * 24 + h] = make_float2(dt, dt * A);   // (dt, log dA)
        }
    }
}

// ---------- SSD local kernel: per (b,h,chunk): G -> M -> Y, s_out ----------
__global__ __launch_bounds__(256)
void ssd_local_kernel(const unsigned short* __restrict__ Brow,
                      const unsigned short* __restrict__ Crow,
                      const float2* __restrict__ dtdA,
                      const unsigned short* __restrict__ xT,
                      const unsigned short* __restrict__ bT,
                      const float* __restrict__ Dh,
                      float* __restrict__ yb,
                      unsigned short* __restrict__ sst,
                      float* __restrict__ Pbuf) {
    extern __shared__ __align__(16) char smem[];
    __bf16* Bs  = (__bf16*)smem;                 // 128 x SLD; later Xt(0:17408)+Xtw(17408:34816)
    __bf16* Cs  = (__bf16*)(smem + 34816);       // 128 x SLD; later Ms
    float*  Lc  = (float*)(smem + 69632);        // 128
    float*  dtl = (float*)(smem + 70144);        // 128

    const int tid = threadIdx.x;
    const int c   = blockIdx.x & 15;
    const int bh  = blockIdx.x >> 4;
    const int b   = bh / 24, h = bh % 24;
    const int t0g = b * 2048 + c * QCHUNK;
    const int wave = tid >> 6, lane = tid & 63;
    const int lr = lane & 15, q = lane >> 4;

    for (int cc = tid; cc < 2048; cc += 256) {
        int r = cc >> 4, c8 = (cc & 15) << 3;
        *(uint4*)(Bs + r * SLD + c8) = *(const uint4*)(Brow + ((size_t)(t0g + r)) * 128 + c8);
        *(uint4*)(Cs + r * SLD + c8) = *(const uint4*)(Crow + ((size_t)(t0g + r)) * 128 + c8);
    }
    if (tid < 128) {
        float2 dd = dtdA[((size_t)t0g + tid) * 24 + h];
        dtl[tid] = dd.x;
        Lc[tid]  = dd.y;     // log dA
    }
    __syncthreads();
    for (int off = 1; off < 128; off <<= 1) {
        float v = 0.f;
        if (tid < 128 && tid >= off) v = Lc[tid - off];
        __syncthreads();
        if (tid < 128) Lc[tid] += v;
        __syncthreads();
    }

    // P1: G = Cs . Bs^T
    const int wm = (wave & 1) * 64, wn = (wave >> 1) * 64;
    f32x4 g[4][4] = {};
    #pragma unroll
    for (int k0 = 0; k0 < 128; k0 += 32) {
        bf16x8 af[4], bfr[4];
        #pragma unroll
        for (int t = 0; t < 4; ++t) {
            af[t]  = *(const bf16x8*)(Cs + (wm + t * 16 + lr) * SLD + k0 + q * 8);
            bfr[t] = *(const bf16x8*)(Bs + (wn + t * 16 + lr) * SLD + k0 + q * 8);
        }
        #pragma unroll
        for (int ti = 0; ti < 4; ++ti)
            #pragma unroll
            for (int tj = 0; tj < 4; ++tj)
                g[ti][tj] = __builtin_amdgcn_mfma_f32_16x16x32_bf16(af[ti], bfr[tj], g[ti][tj], 0, 0, 0);
    }
    __syncthreads();

    // P5: masked scale -> Ms[t][tau]
    __bf16* Ms = Cs;
    {
        float lt_[4], dt_[4];
        #pragma unroll
        for (int tj = 0; tj < 4; ++tj) {
            int tau = wn + tj * 16 + lr;
            lt_[tj] = Lc[tau];
            dt_[tj] = dtl[tau];
        }
        #pragma unroll
        for (int ti = 0; ti < 4; ++ti) {
            #pragma unroll
            for (int r = 0; r < 4; ++r) {
                int t = wm + ti * 16 + q * 4 + r;
                float Lt = Lc[t];
                #pragma unroll
                for (int tj = 0; tj < 4; ++tj) {
                    int tau = wn + tj * 16 + lr;
                    float mv = (tau <= t) ? g[ti][tj][r] * expf(Lt - lt_[tj]) * dt_[tj] : 0.f;
                    unsigned short u = f2bf(mv);
                    Ms[t * SLD + tau] = *(__bf16*)&u;
                }
            }
        }
    }

    // P3: stage Xt[p][t] and Xtw[p][t]
    __bf16* Xt  = Bs;
    __bf16* Xtw = (__bf16*)(smem + 17408);
    {
        float LQ = Lc[127];
        const unsigned short* xTb = xT + ((size_t)(b * 1536 + h * 64)) * 2048 + c * QCHUNK;
        for (int cc = tid; cc < 1024; cc += 256) {
            int p = cc >> 4, c8 = (cc & 15) << 3;
            uint4 v = *(const uint4*)(xTb + (size_t)p * 2048 + c8);
            *(uint4*)(Xt + p * SLD + c8) = v;
            unsigned short uu[8] = {(unsigned short)(v.x & 0xFFFF), (unsigned short)(v.x >> 16),
                                    (unsigned short)(v.y & 0xFFFF), (unsigned short)(v.y >> 16),
                                    (unsigned short)(v.z & 0xFFFF), (unsigned short)(v.z >> 16),
                                    (unsigned short)(v.w & 0xFFFF), (unsigned short)(v.w >> 16)};
            float w0[8];
            #pragma unroll
            for (int jj = 0; jj < 8; ++jj) {
                int tau = c8 + jj;
                w0[jj] = bf2f(uu[jj]) * expf(LQ - Lc[tau]) * dtl[tau];
            }
            *(uint4*)(Xtw + p * SLD + c8) = pack8(make_float4(w0[0], w0[1], w0[2], w0[3]),
                                                  make_float4(w0[4], w0[5], w0[6], w0[7]));
        }
    }
    __syncthreads();

    // P4: s_out[n][p] = bT . Xtw^T
    {
        f32x4 so[2][4] = {};
        const unsigned short* bTb = bT + ((size_t)(b * 128)) * 2048 + c * QCHUNK;
        #pragma unroll
        for (int k0 = 0; k0 < 128; k0 += 32) {
            bf16x8 af[2], bfr[4];
            #pragma unroll
            for (int ti = 0; ti < 2; ++ti) {
                int n = wave * 32 + ti * 16 + lr;
                af[ti] = *(const bf16x8*)(bTb + (size_t)n * 2048 + k0 + q * 8);
            }
            #pragma unroll
            for (int tj = 0; tj < 4; ++tj)
                bfr[tj] = *(const bf16x8*)(Xtw + (tj * 16 + lr) * SLD + k0 + q * 8);
            #pragma unroll
            for (int ti = 0; ti < 2; ++ti)
                #pragma unroll
                for (int tj = 0; tj < 4; ++tj)
                    so[ti][tj] = __builtin_amdgcn_mfma_f32_16x16x32_bf16(af[ti], bfr[tj], so[ti][tj], 0, 0, 0);
        }
        unsigned short* sb = sst + ((size_t)(bh * NCHUNK + c)) * 8192;
        #pragma unroll
        for (int ti = 0; ti < 2; ++ti) {
            #pragma unroll
            for (int r = 0; r < 4; ++r) {
                int n = wave * 32 + ti * 16 + q * 4 + r;
                #pragma unroll
                for (int tj = 0; tj < 4; ++tj) {
                    int p = tj * 16 + lr;
                    sb[n * 64 + p] = f2bf(so[ti][tj][r]);
                }
            }
        }
        if (tid == 0) Pbuf[bh * NCHUNK + c] = expf(Lc[127]);
    }

    // P6: Y[t][p] = Ms . Xt^T  (+ D skip)
    {
        f32x4 ya[2][4] = {};
        #pragma unroll
        for (int k0 = 0; k0 < 128; k0 += 32) {
            bf16x8 af[2], bfr[4];
            #pragma unroll
            for (int ti = 0; ti < 2; ++ti)
                af[ti] = *(const bf16x8*)(Ms + (wave * 32 + ti * 16 + lr) * SLD + k0 + q * 8);
            #pragma unroll
            for (int tj = 0; tj < 4; ++tj)
                bfr[tj] = *(const bf16x8*)(Xt + (tj * 16 + lr) * SLD + k0 + q * 8);
            #pragma unroll
            for (int ti = 0; ti < 2; ++ti)
                #pragma unroll
                for (int tj = 0; tj < 4; ++tj)
                    ya[ti][tj] = __builtin_amdgcn_mfma_f32_16x16x32_bf16(af[ti], bfr[tj], ya[ti][tj], 0, 0, 0);
        }
        float Dv = Dh[h];
        float* ybb = yb + (size_t)t0g * 1536 + h * 64;
        #pragma unroll
        for (int ti = 0; ti < 2; ++ti) {
            #pragma unroll
            for (int r = 0; r < 4; ++r) {
                int t = wave * 32 + ti * 16 + q * 4 + r;
                #pragma unroll
                for (int tj = 0; tj < 4; ++tj) {
                    int p = tj * 16 + lr;
                    __bf16 xb = Xt[p * SLD + t];
                    float xv = bf2f(*(unsigned short*)&xb);
                    ybb[(size_t)t * 1536 + p] = ya[ti][tj][r] + Dv * xv;
                }
            }
        }
    }
}

// ---------- combine ----------
__global__ __launch_bounds__(256)
void combine_kernel(const unsigned short* __restrict__ sst,
                    unsigned short* __restrict__ sstT,
                    const float* __restrict__ Pbuf) {
    int flat = blockIdx.x * 256 + threadIdx.x;
    int bh = flat >> 13;
    int pn = flat & 8191;
    int n = pn >> 6, p = pn & 63;
    const unsigned short* sb = sst + (size_t)bh * NCHUNK * 8192;
    unsigned short* tb = sstT + (size_t)bh * NCHUNK * 8192 + p * 128 + n;
    const float* Pb = Pbuf + bh * NCHUNK;
    float s = 0.f;
    #pragma unroll
    for (int c = 0; c < NCHUNK; ++c) {
        float tmp = bf2f(sb[(size_t)c * 8192 + pn]);
        tb[(size_t)c * 8192] = f2bf(s);
        s = Pb[c] * s + tmp;
    }
}

// ---------- SSD inter kernel ----------
__global__ __launch_bounds__(256)
void ssd_inter_kernel(const unsigned short* __restrict__ Crow,
                      const float2* __restrict__ dtdA,
                      const unsigned short* __restrict__ sstT,
                      float* __restrict__ yb) {
    __shared__ __align__(16) __bf16 Cs[128 * SLD];
    __shared__ __align__(16) __bf16 St[64 * SLD];
    __shared__ float Lc[128];

    const int tid = threadIdx.x;
    const int blk = blockIdx.x;
    const int bh = blk / 15;
    const int c  = blk % 15 + 1;
    const int b = bh / 24, h = bh % 24;
    const int t0g = b * 2048 + c * QCHUNK;
    const int wave = tid >> 6, lane = tid & 63;
    const int lr = lane & 15, q = lane >> 4;

    for (int cc = tid; cc < 2048; cc += 256) {
        int r = cc >> 4, c8 = (cc & 15) << 3;
        *(uint4*)(Cs + r * SLD + c8) = *(const uint4*)(Crow + ((size_t)(t0g + r)) * 128 + c8);
    }
    const unsigned short* stb = sstT + ((size_t)(bh * NCHUNK + c)) * 8192;
    for (int cc = tid; cc < 1024; cc += 256) {
        int p = cc >> 4, c8 = (cc & 15) << 3;
        *(uint4*)(St + p * SLD + c8) = *(const uint4*)(stb + p * 128 + c8);
    }
    if (tid < 128) Lc[tid] = dtdA[((size_t)t0g + tid) * 24 + h].y;
    __syncthreads();
    for (int off = 1; off < 128; off <<= 1) {
        float v = 0.f;
        if (tid < 128 && tid >= off) v = Lc[tid - off];
        __syncthreads();
        if (tid < 128) Lc[tid] += v;
        __syncthreads();
    }

    f32x4 ya[2][4] = {};
    #pragma unroll
    for (int k0 = 0; k0 < 128; k0 += 32) {
        bf16x8 af[2], bfr[4];
        #pragma unroll
        for (int ti = 0; ti < 2; ++ti)
            af[ti] = *(const bf16x8*)(Cs + (wave * 32 + ti * 16 + lr) * SLD + k0 + q * 8);
        #pragma unroll
        for (int tj = 0; tj < 4; ++tj)
            bfr[tj] = *(const bf16x8*)(St + (tj * 16 + lr) * SLD + k0 + q * 8);
        #pragma unroll
        for (int ti = 0; ti < 2; ++ti)
            #pragma unroll
            for (int tj = 0; tj < 4; ++tj)
                ya[ti][tj] = __builtin_amdgcn_mfma_f32_16x16x32_bf16(af[ti], bfr[tj], ya[ti][tj], 0, 0, 0);
    }
    float* ybb = yb + (size_t)t0g * 1536 + h * 64;
    #pragma unroll
    for (int ti = 0; ti < 2; ++ti) {
        #pragma unroll
        for (int r = 0; r < 4; ++r) {
            int t = wave * 32 + ti * 16 + q * 4 + r;
            float sc = expf(Lc[t]);
            #pragma unroll
            for (int tj = 0; tj < 4; ++tj) {
                int p = tj * 16 + lr;
                float* yp = ybb + (size_t)t * 1536 + p;
                *yp = *yp + sc * ya[ti][tj][r];
            }
        }
    }
}

// ---------- gated RMSNorm: writes bf16 into zx cols [1536,3072) ----------
__global__ __launch_bounds__(256)
void norm_kernel(const float* __restrict__ yb,
                 unsigned short* __restrict__ zx,
                 const float* __restrict__ nw) {
    int row = blockIdx.x;
    const float* yr = yb + (size_t)row * 1536;
    unsigned short* zr = zx + (size_t)row * 3352;
    int tid = threadIdx.x;
    float u[6];
    float ss = 0.f;
    #pragma unroll
    for (int i = 0; i < 6; ++i) {
        int c = tid + i * 256;
        float z = bf2f(zr[c]);
        float uu = yr[c] * (z / (1.f + expf(-z)));
        u[i] = uu;
        ss += uu * uu;
    }
    #pragma unroll
    for (int m = 1; m < 64; m <<= 1) ss += __shfl_xor(ss, m);
    __shared__ float red[4];
    if ((tid & 63) == 0) red[tid >> 6] = ss;
    __syncthreads();
    float tot = red[0] + red[1] + red[2] + red[3];
    float inv = rsqrtf(tot * (1.f / 1536.f) + 1e-5f);
    #pragma unroll
    for (int i = 0; i < 6; ++i) {
        int c = tid + i * 256;
        zr[1536 + c] = f2bf(u[i] * inv * nw[c]);
    }
}

// ---------- launch ----------
extern "C" void kernel_launch(void* const* d_in, const int* in_sizes, int n_in,
                              void* d_out, int out_size, void* d_ws, size_t ws_size,
                              hipStream_t stream) {
    const float* x       = (const float*)d_in[0];
    const float* w_in    = (const float*)d_in[1];
    const float* conv_w  = (const float*)d_in[2];
    const float* conv_b  = (const float*)d_in[3];
    const float* dt_bias = (const float*)d_in[4];
    const float* A_log   = (const float*)d_in[5];
    const float* Dp      = (const float*)d_in[6];
    const float* nw      = (const float*)d_in[7];
    const float* w_out   = (const float*)d_in[8];
    float* out = (float*)d_out;

    char* ws = (char*)d_ws;
    const size_t off_zx   = 0;                        // 8192*3352 bf16 = 54,919,168
    const size_t off_A    = off_zx + 54919168;        // region A (58,720,256 reserved)
    const size_t off_xT   = off_A;                    // 25,165,824 (sstT + w_out_bf alias later)
    const size_t off_bT   = off_A + 25165824;         // 2,097,152
    const size_t off_Brow = off_A + 27262976;         // 2,097,152
    const size_t off_Crow = off_A + 29360128;         // 2,097,152
    const size_t off_dtdA = off_A + 58720256;         // 1,572,864
    const size_t off_y    = off_dtdA + 1572864;       // 50,331,648 (x_bf aliases head)
    const size_t off_sst  = off_y + 50331648;         // 25,165,824 (w_in_bf aliases head)
    const size_t off_P    = off_sst + 25165824;       // 6,144

    unsigned short* zx   = (unsigned short*)(ws + off_zx);
    unsigned short* xT   = (unsigned short*)(ws + off_xT);
    unsigned short* bT   = (unsigned short*)(ws + off_bT);
    unsigned short* Brow = (unsigned short*)(ws + off_Brow);
    unsigned short* Crow = (unsigned short*)(ws + off_Crow);
    float2* dtdA = (float2*)(ws + off_dtdA);
    float* yb    = (float*)(ws + off_y);
    unsigned short* sst  = (unsigned short*)(ws + off_sst);
    unsigned short* sstT = xT;                        // xT dead after ssd_local
    float* Pbuf = (float*)(ws + off_P);

    // transient aliases (dead regions at time of use)
    unsigned short* x_bf     = (unsigned short*)(ws + off_y);    // gemm1 only (before yb written)
    unsigned short* w_in_bf  = (unsigned short*)(ws + off_sst);  // gemm1 only (before sst written)
    unsigned short* w_out_bf = (unsigned short*)(ws + off_xT);   // written after sstT dead (step 7.5)

    static bool attr_set = false;
    if (!attr_set) {
        hipFuncSetAttribute((const void*)ssd_local_kernel,
                            hipFuncAttributeMaxDynamicSharedMemorySize, 70656);
        attr_set = true;
    }

    // 0. convert x, w_in (padded to 3456 rows) -> bf16
    convert_kernel<<<4368, 256, 0, stream>>>(x, w_in, x_bf, w_in_bf);
    // 1. in_proj (M=8192, N=3352 padded 3456, K=768)
    gemm_lds<false, false><<<64 * 27, 256, 0, stream>>>(x_bf, w_in_bf, zx, nullptr, 27, 3352, 768, 768);
    // 2. fused conv + silu + layout (replaces conv_silu + transpose; cv eliminated)
    conv_fused_kernel<<<3584, 256, 0, stream>>>(zx, conv_w, conv_b, xT, bT, Brow, Crow);
    // 3. dt / log-dA (full f32)
    dt_kernel<<<8192, 64, 0, stream>>>(x, w_in, dt_bias, A_log, dtdA);
    // 4. SSD local
    ssd_local_kernel<<<1536, 256, 70656, stream>>>(Brow, Crow, dtdA, xT, bT, Dp, yb, sst, Pbuf);
    // 5. combine
    combine_kernel<<<3072, 256, 0, stream>>>(sst, sstT, Pbuf);
    // 6. SSD inter
    ssd_inter_kernel<<<1440, 256, 0, stream>>>(Crow, dtdA, sstT, yb);
    // 6.5 convert w_out -> bf16 (xT/sstT region dead now)
    convert_wout_kernel<<<576, 256, 0, stream>>>(w_out, w_out_bf);
    // 7. gated RMSNorm -> bf16 into zx cols [1536,3072)
    norm_kernel<<<8192, 256, 0, stream>>>(yb, zx, nw);
    // 8. out_proj + residual
    gemm_lds<true, true><<<64 * 6, 256, 0, stream>>>(zx + 1536, w_out_bf, out, x, 6, 768, 1536, 3352);
}